// Round 6
// baseline (523.342 us; speedup 1.0000x reference)
//
#include <hip/hip_runtime.h>

// Sggnn_23218593202512 — round 19: un-fuse + 8-phase the affinity path.
// R18's 8-phase worker gemm dropped h/t below gemm_aff (110.6us, MfmaUtil
// 12.8%) which is now the top dispatch and still has the R12 2-barrier +
// pair-fused-VALU structure (the exact pattern R17 proved slow). Fix =
// same treatment as R17/R18: (1) dgprep materializes dg for the 136
// canonical gallery tile-pairs as bf16 [34816,1024] (71MB, written into
// probe-phase scratch which is dead during the affinity phase) + an
// affmap[row]=g1*256+g2 target table; (2) the affinity gemm becomes the
// standard 8-phase gemm256 (A=dgc, B=sfcT, fused lrelu*bn*scl_W epilogue
// -> atomicAdd w_acc[affmap[r]]). gemm256 gains one affmap param
// (nullptr on worker call sites). Same BK/MFMA K-order and bf16 rounding
// point as old gemm_aff -> numerics unchanged. gemm_aff deleted.
// dprep / prep / wtrans / wconv / finout / worker launches byte-identical.

typedef __bf16 bf16;
typedef __attribute__((ext_vector_type(8))) __bf16 bf16x8;
typedef __attribute__((ext_vector_type(4))) float f32x4;

#define EPSV 1e-5f

__device__ __forceinline__ void async_load16(const bf16* g, bf16* l) {
    __builtin_amdgcn_global_load_lds(
        (const __attribute__((address_space(1))) void*)g,
        (__attribute__((address_space(3))) void*)l, 16, 0, 0);
}

__global__ __launch_bounds__(256) void prep_kernel(
    const float* __restrict__ g, const float* __restrict__ b,
    const float* __restrict__ m, const float* __restrict__ v,
    const float* __restrict__ bias, float* __restrict__ scale,
    float* __restrict__ offset, int n)
{
    int i = blockIdx.x * 256 + threadIdx.x;
    if (i >= n) return;
    float s = g[i] / sqrtf(v[i] + EPSV);
    float o = b[i] - m[i] * s;
    if (bias) o += bias[i] * s;
    scale[i] = s;
    offset[i] = o;
}

__global__ __launch_bounds__(256) void wtrans_kernel(
    const float* __restrict__ in, bf16* __restrict__ out, int K, int N)
{
    int k = blockIdx.x * 256 + threadIdx.x;
    int n = blockIdx.y;
    out[(size_t)n * K + k] = (bf16)in[(size_t)k * N + n];
}

// wT[g2*256+g1] = bf16(w[g1][g2] + scl_b); only g-tiles ta<=tb computed,
// mirror otherwise (w symmetric). [R11/R12-verified]
__global__ __launch_bounds__(256) void wconv_kernel(
    const float* __restrict__ w_acc, const float* __restrict__ sclb,
    bf16* __restrict__ wT)
{
    int tid = blockIdx.x * 256 + threadIdx.x;
    int g2 = tid >> 8, g1 = tid & 255;
    int idx = ((g1 >> 4) <= (g2 >> 4)) ? (g1 * 256 + g2) : (g2 * 256 + g1);
    wT[tid] = (bf16)(w_acc[idx] + sclb[0]);
}

__global__ __launch_bounds__(256) void finout_kernel(
    const float* __restrict__ acc, const float* __restrict__ clsb,
    float* __restrict__ out)
{
    int i = blockIdx.x * 256 + threadIdx.x;
    out[i] = acc[i] + clsb[0];
}

// d[r][k] = bf16((f_p[gr>>8][k] - f_g[gr&255][k])^2 * ps[k] + po[k]),
// gr = rowOff + r. One bf16x8 per thread; writes coalesced 16B.
__global__ __launch_bounds__(256) void dprep_kernel(
    const float* __restrict__ X, const float* __restrict__ Y,
    const float* __restrict__ ps, const float* __restrict__ po,
    bf16* __restrict__ d, int rowOff)
{
    int t  = blockIdx.x * 256 + threadIdx.x;
    int k0 = (t & 127) * 8;           // 128 threads span one 1024-wide row
    int r  = t >> 7;
    int gr = rowOff + r;
    const float* xp = X + (size_t)(gr >> 8) * 1024 + k0;
    const float* yp = Y + (size_t)(gr & 255) * 1024 + k0;
    f32x4 x0 = *(const f32x4*)xp, x1 = *(const f32x4*)(xp + 4);
    f32x4 y0 = *(const f32x4*)yp, y1 = *(const f32x4*)(yp + 4);
    f32x4 sa = *(const f32x4*)(ps + k0), sb = *(const f32x4*)(ps + k0 + 4);
    f32x4 oa = *(const f32x4*)(po + k0), ob = *(const f32x4*)(po + k0 + 4);
    bf16x8 dv;
#pragma unroll
    for (int j = 0; j < 4; ++j) {
        float d0 = x0[j] - y0[j];
        float d1 = x1[j] - y1[j];
        dv[j]     = (bf16)(d0 * d0 * sa[j] + oa[j]);
        dv[j + 4] = (bf16)(d1 * d1 * sb[j] + ob[j]);
    }
    *(bf16x8*)&d[(size_t)r * 1024 + k0] = dv;
}

// dg for canonical gallery tile-pairs. Local row r of this chunk maps to
// pair-tile p = tileOff + (r>>8) -> triangular (ta,tb); rr = r&255:
// g1 = ta*16 + (rr>>4), g2 = tb*16 + (rr&15)  [same mapping as old
// gemm_aff staging]. Writes dg[r][k] bf16 and affmap[r] = g1*256+g2.
__global__ __launch_bounds__(256) void dgprep_kernel(
    const float* __restrict__ X,
    const float* __restrict__ ps, const float* __restrict__ po,
    bf16* __restrict__ dg, int* __restrict__ affmap, int tileOff)
{
    int t  = blockIdx.x * 256 + threadIdx.x;
    int k0 = (t & 127) * 8;
    int r  = t >> 7;
    int p  = tileOff + (r >> 8);
    int ta = 0, rem = p;
    while (rem >= 16 - ta) { rem -= 16 - ta; ++ta; }
    int tb = ta + rem;
    int rr = r & 255;
    int g1 = ta * 16 + (rr >> 4), g2 = tb * 16 + (rr & 15);
    const float* xp = X + (size_t)g1 * 1024 + k0;
    const float* yp = X + (size_t)g2 * 1024 + k0;
    f32x4 x0 = *(const f32x4*)xp, x1 = *(const f32x4*)(xp + 4);
    f32x4 y0 = *(const f32x4*)yp, y1 = *(const f32x4*)(yp + 4);
    f32x4 sa = *(const f32x4*)(ps + k0), sb = *(const f32x4*)(ps + k0 + 4);
    f32x4 oa = *(const f32x4*)(po + k0), ob = *(const f32x4*)(po + k0 + 4);
    bf16x8 dv;
#pragma unroll
    for (int j = 0; j < 4; ++j) {
        float d0 = x0[j] - y0[j];
        float d1 = x1[j] - y1[j];
        dv[j]     = (bf16)(d0 * d0 * sa[j] + oa[j]);
        dv[j + 4] = (bf16)(d1 * d1 * sb[j] + ob[j]);
    }
    *(bf16x8*)&dg[(size_t)r * 1024 + k0] = dv;
    if (k0 == 0) affmap[r] = g1 * 256 + g2;
}

// One phase: {ds_read A-quad Q (+ all B if READB) ; STAGE ; VM ;
//             barrier ; lgkmcnt(0) ; setprio(1) 16 MFMA setprio(0) ;
//             barrier}. Q is a literal -> all acc indices compile-time.
#define PHASE(ASB, BSB, Q, READB, STAGE_STMT, VM_STMT)                        \
  {                                                                           \
    if (READB) {                                                              \
      _Pragma("unroll") for (int ni = 0; ni < 4; ++ni) {                      \
        int rc = wcol * 64 + ni * 16 + l16;                                   \
        bfr[ni][0] = *(const bf16x8*)&(BSB)[rc * 64 + (((q) ^ (rc & 7)) * 8)];\
        bfr[ni][1] = *(const bf16x8*)&(BSB)[rc * 64 + (((4 + q) ^ (rc & 7)) * 8)];\
      }                                                                       \
    }                                                                         \
    bf16x8 afq[2][2];                                                         \
    _Pragma("unroll") for (int m2 = 0; m2 < 2; ++m2) {                        \
      int r = wrow * 128 + ((Q) * 2 + m2) * 16 + l16;                         \
      afq[m2][0] = *(const bf16x8*)&(ASB)[r * 64 + (((q) ^ (r & 7)) * 8)];    \
      afq[m2][1] = *(const bf16x8*)&(ASB)[r * 64 + (((4 + q) ^ (r & 7)) * 8)];\
    }                                                                         \
    STAGE_STMT;                                                               \
    VM_STMT;                                                                  \
    __builtin_amdgcn_s_barrier();                                             \
    asm volatile("s_waitcnt lgkmcnt(0)" ::: "memory");                        \
    __builtin_amdgcn_s_setprio(1);                                            \
    _Pragma("unroll") for (int s = 0; s < 2; ++s)                             \
      _Pragma("unroll") for (int m2 = 0; m2 < 2; ++m2)                        \
        _Pragma("unroll") for (int ni = 0; ni < 4; ++ni)                      \
          acc[(Q) * 2 + m2][ni] = __builtin_amdgcn_mfma_f32_16x16x32_bf16(    \
              afq[m2][s], bfr[ni][s], acc[(Q) * 2 + m2][ni], 0, 0, 0);        \
    __builtin_amdgcn_s_setprio(0);                                            \
    __builtin_amdgcn_s_barrier();                                             \
  }

// ---------- gemm256 (R18 8-phase core + R19 affmap epilogue) --------------
// C_z[M,N] = epi(A_z[M,K] @ BT_z[N,K]^T). 256x256 block, 512 thr = 8 waves
// (2 row x 4 col), wave 128x64 (acc[8][4]), BK=64, XOR-swizzled LDS,
// buf0 <-> even K-tiles, buf1 <-> odd K-tiles (64 KiB each, 128 KiB total).
// fuse (fuseW!=0): rs += lrelu(bn(val))*fuseW[col] -> atomicAdd to
//   facc[affmap[r]] if affmap else facc[z*faccStride + r].
__global__ __launch_bounds__(512) void gemm256(
    const bf16* __restrict__ A,
    const bf16* __restrict__ BT,
    bf16* __restrict__ C,
    int K, int N,
    long long batchA, long long batchB, long long batchC,
    const float* __restrict__ scale, const float* __restrict__ offset,
    int lrelu,
    const float* __restrict__ fuseW, float* __restrict__ facc,
    long long faccStride,
    const int* __restrict__ affmap)
{
    __shared__ bf16 As[2 * 256 * 64];   // 64 KiB (buf0|buf1)
    __shared__ bf16 Bs[2 * 256 * 64];   // 64 KiB (buf0|buf1)
    const int tid  = threadIdx.x;
    const int lane = tid & 63;
    const int wave = tid >> 6;
    const int wrow = wave >> 2, wcol = wave & 3;
    const int q = lane >> 4, l16 = lane & 15;
    const int z = blockIdx.z;

    // XCD-aware bijective swizzle (x fastest in dispatch order).
    int bx = blockIdx.x, by = blockIdx.y;
    {
        int nwg = gridDim.x * gridDim.y;
        if (gridDim.z == 1 && (nwg & 7) == 0) {
            int lin = by * gridDim.x + bx;
            int cpx = nwg >> 3;
            int s = (lin & 7) * cpx + (lin >> 3);
            bx = s % gridDim.x;
            by = s / gridDim.x;
        }
    }
    const int row0 = by * 256;
    const int col0 = bx * 256;

    const bf16* Ap = A + (size_t)z * (size_t)batchA;
    const bf16* Bp = BT + (size_t)z * (size_t)batchB;

    f32x4 acc[8][4];
#pragma unroll
    for (int mi = 0; mi < 8; ++mi)
#pragma unroll
        for (int ni = 0; ni < 4; ++ni)
#pragma unroll
            for (int e = 0; e < 4; ++e) acc[mi][ni][e] = 0.f;

    // stage one half-tile (rows h*128..h*128+127) = 2 async loads/thread
    auto stageA2 = [&](int kk, int buf, int h) {
#pragma unroll
        for (int tt = 0; tt < 2; ++tt) {
            int idx = (2 * h + tt) * 512 + tid;
            int r = idx >> 3, sch = idx & 7;
            int gch = sch ^ (r & 7);
            async_load16(Ap + (size_t)(row0 + r) * K + kk + gch * 8,
                         &As[buf * 16384 + idx * 8]);
        }
    };
    auto stageB2 = [&](int kk, int buf, int h) {
#pragma unroll
        for (int tt = 0; tt < 2; ++tt) {
            int idx = (2 * h + tt) * 512 + tid;
            int r = idx >> 3, sch = idx & 7;
            int gch = sch ^ (r & 7);
            async_load16(Bp + (size_t)(col0 + r) * K + kk + gch * 8,
                         &Bs[buf * 16384 + idx * 8]);
        }
    };

    // prologue: tile0 (A+B) -> buf0, tile1 B -> buf1  (6 halves, 12 loads)
    stageA2(0, 0, 0); stageA2(0, 0, 1);
    stageB2(0, 0, 0); stageB2(0, 0, 1);
    stageB2(64, 1, 0); stageB2(64, 1, 1);
    // wait buf0's 8 loads (oldest); buf1.B's 4 stay in flight
    asm volatile("s_waitcnt vmcnt(4)" ::: "memory");
    __builtin_amdgcn_s_barrier();

    bf16x8 bfr[4][2];
    const bf16* A0 = As;          const bf16* B0 = Bs;
    const bf16* A1 = As + 16384;  const bf16* B1 = Bs + 16384;
    const int nt = K >> 6;        // even for all call sites (16 or 4)
    for (int i2 = 0; i2 < nt; i2 += 2) {
        const int kk1 = (i2 + 1) << 6, kk2 = (i2 + 2) << 6,
                  kk3 = (i2 + 3) << 6;
        const bool more = (i2 + 2) < nt;   // tiles i2+2 AND i2+3 exist
        // ---- tile i2 from buf0 (phases 1-4) ----
        PHASE(A0, B0, 0, true,  { stageA2(kk1, 1, 0); }, {});
        PHASE(A0, B0, 1, false, { stageA2(kk1, 1, 1); }, {});
        PHASE(A0, B0, 2, false, { if (more) stageB2(kk2, 0, 0); }, {});
        PHASE(A0, B0, 3, false, { if (more) stageB2(kk2, 0, 1); },
              { if (more)
                    asm volatile("s_waitcnt vmcnt(4)" ::: "memory");
                else
                    asm volatile("s_waitcnt vmcnt(0)" ::: "memory"); });
        // ---- tile i2+1 from buf1 (phases 5-8) ----
        PHASE(A1, B1, 0, true,  { if (more) stageA2(kk2, 0, 0); }, {});
        PHASE(A1, B1, 1, false, { if (more) stageA2(kk2, 0, 1); }, {});
        PHASE(A1, B1, 2, false, { if (more) stageB2(kk3, 1, 0); }, {});
        PHASE(A1, B1, 3, false, { if (more) stageB2(kk3, 1, 1); },
              { if (more)
                    asm volatile("s_waitcnt vmcnt(4)" ::: "memory"); });
    }

    // C/D layout (m89-verified): col = lane&15, row = (lane>>4)*4 + reg
    if (fuseW) {
#pragma unroll
        for (int mi = 0; mi < 8; ++mi)
#pragma unroll
            for (int i = 0; i < 4; ++i) {
                float rs = 0.f;
#pragma unroll
                for (int ni = 0; ni < 4; ++ni) {
                    int cc = col0 + wcol * 64 + ni * 16 + l16;
                    float val = acc[mi][ni][i] * scale[cc] + offset[cc];
                    val = val > 0.f ? val : 0.1f * val;
                    rs += val * fuseW[cc];
                }
                rs += __shfl_xor(rs, 1, 64);
                rs += __shfl_xor(rs, 2, 64);
                rs += __shfl_xor(rs, 4, 64);
                rs += __shfl_xor(rs, 8, 64);
                if (l16 == 0) {
                    int r = row0 + wrow * 128 + mi * 16 + q * 4 + i;
                    float* dst = affmap ? (facc + affmap[r])
                                        : (facc + (size_t)z * faccStride + r);
                    atomicAdd(dst, rs);
                }
            }
        return;
    }
    bf16* Cp = C + (size_t)z * (size_t)batchC;
#pragma unroll
    for (int mi = 0; mi < 8; ++mi)
#pragma unroll
        for (int ni = 0; ni < 4; ++ni)
#pragma unroll
            for (int i = 0; i < 4; ++i) {
                int r = row0 + wrow * 128 + mi * 16 + q * 4 + i;
                int cc = col0 + wcol * 64 + ni * 16 + l16;
                float val = acc[mi][ni][i];
                if (scale) val = val * scale[cc] + offset[cc];
                if (lrelu) val = val > 0.f ? val : 0.1f * val;
                Cp[(size_t)r * N + cc] = (bf16)val;
            }
}

extern "C" void kernel_launch(void* const* d_in, const int* in_sizes, int n_in,
                              void* d_out, int out_size, void* d_ws, size_t ws_size,
                              hipStream_t stream)
{
    const float* f_p   = (const float*)d_in[0];
    const float* f_g   = (const float*)d_in[1];
    const float* bn_g  = (const float*)d_in[2];
    const float* bn_b  = (const float*)d_in[3];
    const float* bn_m  = (const float*)d_in[4];
    const float* bn_v  = (const float*)d_in[5];
    const float* rf_W1 = (const float*)d_in[6];
    const float* rf_b1 = (const float*)d_in[7];
    const float* rf1_g = (const float*)d_in[8];
    const float* rf1_b = (const float*)d_in[9];
    const float* rf1_m = (const float*)d_in[10];
    const float* rf1_v = (const float*)d_in[11];
    const float* rf_W2 = (const float*)d_in[12];
    const float* rf_b2 = (const float*)d_in[13];
    const float* rf2_g = (const float*)d_in[14];
    const float* rf2_b = (const float*)d_in[15];
    const float* rf2_m = (const float*)d_in[16];
    const float* rf2_v = (const float*)d_in[17];
    const float* sfc_W = (const float*)d_in[18];
    const float* sfc_b = (const float*)d_in[19];
    const float* sbn_g = (const float*)d_in[20];
    const float* sbn_b = (const float*)d_in[21];
    const float* sbn_m = (const float*)d_in[22];
    const float* sbn_v = (const float*)d_in[23];
    const float* scl_W = (const float*)d_in[24];
    const float* scl_b = (const float*)d_in[25];
    const float* ffc_W = (const float*)d_in[26];
    const float* ffc_b = (const float*)d_in[27];
    const float* fbn_g = (const float*)d_in[28];
    const float* fbn_b = (const float*)d_in[29];
    const float* fbn_m = (const float*)d_in[30];
    const float* fbn_v = (const float*)d_in[31];
    const float* cls_W = (const float*)d_in[32];
    const float* cls_b = (const float*)d_in[33];

    const size_t MB = 1ull << 20;
    char* ws = (char*)d_ws;
    float* SC      = (float*)(ws);
    float *s0 = SC,        *o0 = SC + 1024;
    float *s1 = SC + 2048, *o1 = SC + 3072;
    float *s2 = SC + 4096, *o2 = SC + 5120;
    float *s3 = SC + 6144, *o3 = SC + 6656;
    float *s4 = SC + 7168, *o4 = SC + 7680;
    float* w_acc   = (float*)(ws + 65536);       // 256 KiB
    float* out_acc = (float*)(ws + 327680);      // 128 KiB
    bf16* wT       = (bf16*)(ws + 458752);       // 128 KiB
    int*  affmap   = (int*)(ws + 589824);        // 139 KiB (34816 ints)
    bf16* W1T      = (bf16*)(ws + 1 * MB);
    bf16* W2T      = (bf16*)(ws + 3 * MB);
    bf16* sfcT     = (bf16*)(ws + 5 * MB);
    bf16* ffcT     = (bf16*)(ws + 6 * MB);

    int nc;
    if      (ws_size >= 170 * MB) nc = 1;        // confirmed since R3
    else if (ws_size >= 90 * MB)  nc = 2;
    else                          nc = 4;
    const int pc = 128 / nc;
    const int R  = pc * 256;
    const size_t hbytes = (size_t)R * 1024 * 2;
    bf16* bufA = (bf16*)(ws + 8 * MB);                    // h
    bf16* bufB = (bf16*)(ws + 8 * MB + hbytes);           // d, then t
    bf16* bufC = (bf16*)(ws + 8 * MB + 2 * hbytes);       // uT [pc][512][256]

    // 1. BN folds
    prep_kernel<<<dim3(4), 256, 0, stream>>>(bn_g, bn_b, bn_m, bn_v, nullptr, s0, o0, 1024);
    prep_kernel<<<dim3(4), 256, 0, stream>>>(rf1_g, rf1_b, rf1_m, rf1_v, rf_b1, s1, o1, 1024);
    prep_kernel<<<dim3(4), 256, 0, stream>>>(rf2_g, rf2_b, rf2_m, rf2_v, rf_b2, s2, o2, 1024);
    prep_kernel<<<dim3(2), 256, 0, stream>>>(sbn_g, sbn_b, sbn_m, sbn_v, sfc_b, s3, o3, 512);
    prep_kernel<<<dim3(2), 256, 0, stream>>>(fbn_g, fbn_b, fbn_m, fbn_v, ffc_b, s4, o4, 512);

    // 2. weight transposes (f32 -> bf16)
    wtrans_kernel<<<dim3(4, 1024), 256, 0, stream>>>(rf_W1, W1T, 1024, 1024);
    wtrans_kernel<<<dim3(4, 1024), 256, 0, stream>>>(rf_W2, W2T, 1024, 1024);
    wtrans_kernel<<<dim3(4, 512), 256, 0, stream>>>(sfc_W, sfcT, 1024, 512);
    wtrans_kernel<<<dim3(4, 512), 256, 0, stream>>>(ffc_W, ffcT, 1024, 512);

    // 3. zero accumulators (w_acc + out_acc contiguous)
    hipMemsetAsync(ws + 65536, 0, 393216, stream);

    // 4. symmetric affinity, un-fused: dgc (canonical tile-pairs, bf16)
    //    into probe-phase scratch (dead here), then 8-phase gemm256 with
    //    fused lrelu*bn*scl_W epilogue -> atomicAdd w_acc[affmap[r]].
    {
        bf16* dgc = (bf16*)(ws + 8 * MB);    // up to 71.3 MB (na=1)
        const int na = (ws_size >= 170 * MB) ? 1 : 2;
        const int TP = 136 / na;             // pair-tiles per chunk
        for (int ai = 0; ai < na; ++ai) {
            const int rows = TP * 256;
            dgprep_kernel<<<dim3(rows / 2), 256, 0, stream>>>(
                f_g, s0, o0, dgc, affmap + ai * TP * 256, ai * TP);
            gemm256<<<dim3(2, rows / 256), 512, 0, stream>>>(
                dgc, sfcT, nullptr, 1024, 512,
                0, 0, 0, s3, o3, 1, scl_W, w_acc, 0,
                affmap + ai * TP * 256);
        }
    }
    // 5. wT[g2][g1] = bf16(w[canon] + scl_b)
    wconv_kernel<<<dim3(256), 256, 0, stream>>>(w_acc, scl_b, wT);

    // 6. probe chunks (all gemms 8-phase; d precomputed into bufB)
    for (int ci = 0; ci < nc; ++ci) {
        // d = bn1((f_p - f_g)^2)        [R,1024] bf16 -> bufB (dead after h)
        dprep_kernel<<<dim3(R / 2), 256, 0, stream>>>(
            f_p, f_g, s0, o0, bufB, ci * R);
        // h = lrelu(rf1(d @ W1 + b1))   [R,1024]
        gemm256<<<dim3(4, R / 256), 512, 0, stream>>>(
            bufB, W1T, bufA, 1024, 1024,
            0, 0, 0, s1, o1, 1, nullptr, nullptr, 0, nullptr);
        // t = lrelu(rf2(h @ W2 + b2))   [R,1024] (overwrites d: dead)
        gemm256<<<dim3(4, R / 256), 512, 0, stream>>>(
            bufA, W2T, bufB, 1024, 1024,
            0, 0, 0, s2, o2, 1, nullptr, nullptr, 0, nullptr);
        // uT_p = ffcT @ t_p^T           [pc][512][256]  (batched)
        gemm256<<<dim3(1, 2, pc), 512, 0, stream>>>(
            ffcT, bufB, bufC, 1024, 256,
            0, (long long)256 * 1024, (long long)512 * 256,
            nullptr, nullptr, 0, nullptr, nullptr, 0, nullptr);
        // feat_p = lrelu(fbn(wT @ uT_p^T + b)) . cls_W -> out_acc  (batched)
        gemm256<<<dim3(2, 1, pc), 512, 0, stream>>>(
            wT, bufC, nullptr, 256, 512,
            0, (long long)512 * 256, 0,
            s4, o4, 1, cls_W, out_acc + (size_t)ci * pc * 256, 256, nullptr);
    }
    // 7. d_out = out_acc + cls_b
    finout_kernel<<<dim3(128), 256, 0, stream>>>(out_acc, cls_b, (float*)d_out);
}

// Round 7
// 510.809 us; speedup vs baseline: 1.0245x; 1.0245x over previous
//
#include <hip/hip_runtime.h>

// Sggnn_23218593202512 — round 20: housekeeping round. R19 was neutral:
// worker gemms hit their documented reference rate (675 TF, m248v2's
// 8ph/2ph=1.10x at K=1024); the 40.5ms affinity dispatch in the counter
// pass is a rocprof replay artifact (timed total 523us can't contain it;
// atomic-heavy kernel + counter replay). Remaining verified-bad items:
// (1) wtrans reads in[k*N+n] at 4KB lane stride (uncoalesced) -> replace
// with LDS-tiled 64x64 transpose (+1 pad, both sides coalesced), ~10-15us
// -> ~2-3us each; (2) 5 tiny prep launches -> 1 fused prep5 launch.
// gemm256 / dprep / dgprep / wconv / finout / all gemm launches
// byte-identical to R19 for clean attribution.

typedef __bf16 bf16;
typedef __attribute__((ext_vector_type(8))) __bf16 bf16x8;
typedef __attribute__((ext_vector_type(4))) float f32x4;

#define EPSV 1e-5f

__device__ __forceinline__ void async_load16(const bf16* g, bf16* l) {
    __builtin_amdgcn_global_load_lds(
        (const __attribute__((address_space(1))) void*)g,
        (__attribute__((address_space(3))) void*)l, 16, 0, 0);
}

// 5 BN folds in one launch. Segments: [0,1024)=bn, [1024,2048)=rf1,
// [2048,3072)=rf2, [3072,3584)=sbn, [3584,4096)=fbn.
struct P5 { const float *g, *b, *m, *v, *bias; float *sc, *of; };
struct P5All { P5 p[5]; };
__global__ __launch_bounds__(256) void prep5_kernel(P5All a)
{
    int i = blockIdx.x * 256 + threadIdx.x;
    int seg, off;
    if      (i < 1024) { seg = 0; off = i; }
    else if (i < 2048) { seg = 1; off = i - 1024; }
    else if (i < 3072) { seg = 2; off = i - 2048; }
    else if (i < 3584) { seg = 3; off = i - 3072; }
    else               { seg = 4; off = i - 3584; }
    const P5& q = a.p[seg];
    float s = q.g[off] / sqrtf(q.v[off] + EPSV);
    float o = q.b[off] - q.m[off] * s;
    if (q.bias) o += q.bias[off] * s;
    q.sc[off] = s;
    q.of[off] = o;
}

// LDS-tiled transpose: out[n*K+k] = bf16(in[k*N+n]). 64x64 f32 tile,
// +1-pad (65) -> conflict-free; both global access sides coalesced.
// Grid: (K/64, N/64).
__global__ __launch_bounds__(256) void wtransT_kernel(
    const float* __restrict__ in, bf16* __restrict__ out, int K, int N)
{
    __shared__ float tile[64][65];
    const int k0 = blockIdx.x * 64, n0 = blockIdx.y * 64;
    const int c = threadIdx.x & 63, r4 = threadIdx.x >> 6;
#pragma unroll
    for (int i = 0; i < 16; ++i) {
        int r = r4 * 16 + i;
        tile[r][c] = in[(size_t)(k0 + r) * N + n0 + c];
    }
    __syncthreads();
#pragma unroll
    for (int i = 0; i < 16; ++i) {
        int r = r4 * 16 + i;
        out[(size_t)(n0 + r) * K + k0 + c] = (bf16)tile[c][r];
    }
}

// wT[g2*256+g1] = bf16(w[g1][g2] + scl_b); only g-tiles ta<=tb computed,
// mirror otherwise (w symmetric). [R11/R12-verified]
__global__ __launch_bounds__(256) void wconv_kernel(
    const float* __restrict__ w_acc, const float* __restrict__ sclb,
    bf16* __restrict__ wT)
{
    int tid = blockIdx.x * 256 + threadIdx.x;
    int g2 = tid >> 8, g1 = tid & 255;
    int idx = ((g1 >> 4) <= (g2 >> 4)) ? (g1 * 256 + g2) : (g2 * 256 + g1);
    wT[tid] = (bf16)(w_acc[idx] + sclb[0]);
}

__global__ __launch_bounds__(256) void finout_kernel(
    const float* __restrict__ acc, const float* __restrict__ clsb,
    float* __restrict__ out)
{
    int i = blockIdx.x * 256 + threadIdx.x;
    out[i] = acc[i] + clsb[0];
}

// d[r][k] = bf16((f_p[gr>>8][k] - f_g[gr&255][k])^2 * ps[k] + po[k]),
// gr = rowOff + r. One bf16x8 per thread; writes coalesced 16B.
__global__ __launch_bounds__(256) void dprep_kernel(
    const float* __restrict__ X, const float* __restrict__ Y,
    const float* __restrict__ ps, const float* __restrict__ po,
    bf16* __restrict__ d, int rowOff)
{
    int t  = blockIdx.x * 256 + threadIdx.x;
    int k0 = (t & 127) * 8;           // 128 threads span one 1024-wide row
    int r  = t >> 7;
    int gr = rowOff + r;
    const float* xp = X + (size_t)(gr >> 8) * 1024 + k0;
    const float* yp = Y + (size_t)(gr & 255) * 1024 + k0;
    f32x4 x0 = *(const f32x4*)xp, x1 = *(const f32x4*)(xp + 4);
    f32x4 y0 = *(const f32x4*)yp, y1 = *(const f32x4*)(yp + 4);
    f32x4 sa = *(const f32x4*)(ps + k0), sb = *(const f32x4*)(ps + k0 + 4);
    f32x4 oa = *(const f32x4*)(po + k0), ob = *(const f32x4*)(po + k0 + 4);
    bf16x8 dv;
#pragma unroll
    for (int j = 0; j < 4; ++j) {
        float d0 = x0[j] - y0[j];
        float d1 = x1[j] - y1[j];
        dv[j]     = (bf16)(d0 * d0 * sa[j] + oa[j]);
        dv[j + 4] = (bf16)(d1 * d1 * sb[j] + ob[j]);
    }
    *(bf16x8*)&d[(size_t)r * 1024 + k0] = dv;
}

// dg for canonical gallery tile-pairs. Local row r of this chunk maps to
// pair-tile p = tileOff + (r>>8) -> triangular (ta,tb); rr = r&255:
// g1 = ta*16 + (rr>>4), g2 = tb*16 + (rr&15). Writes dg[r][k] bf16 and
// affmap[r] = g1*256+g2.
__global__ __launch_bounds__(256) void dgprep_kernel(
    const float* __restrict__ X,
    const float* __restrict__ ps, const float* __restrict__ po,
    bf16* __restrict__ dg, int* __restrict__ affmap, int tileOff)
{
    int t  = blockIdx.x * 256 + threadIdx.x;
    int k0 = (t & 127) * 8;
    int r  = t >> 7;
    int p  = tileOff + (r >> 8);
    int ta = 0, rem = p;
    while (rem >= 16 - ta) { rem -= 16 - ta; ++ta; }
    int tb = ta + rem;
    int rr = r & 255;
    int g1 = ta * 16 + (rr >> 4), g2 = tb * 16 + (rr & 15);
    const float* xp = X + (size_t)g1 * 1024 + k0;
    const float* yp = X + (size_t)g2 * 1024 + k0;
    f32x4 x0 = *(const f32x4*)xp, x1 = *(const f32x4*)(xp + 4);
    f32x4 y0 = *(const f32x4*)yp, y1 = *(const f32x4*)(yp + 4);
    f32x4 sa = *(const f32x4*)(ps + k0), sb = *(const f32x4*)(ps + k0 + 4);
    f32x4 oa = *(const f32x4*)(po + k0), ob = *(const f32x4*)(po + k0 + 4);
    bf16x8 dv;
#pragma unroll
    for (int j = 0; j < 4; ++j) {
        float d0 = x0[j] - y0[j];
        float d1 = x1[j] - y1[j];
        dv[j]     = (bf16)(d0 * d0 * sa[j] + oa[j]);
        dv[j + 4] = (bf16)(d1 * d1 * sb[j] + ob[j]);
    }
    *(bf16x8*)&dg[(size_t)r * 1024 + k0] = dv;
    if (k0 == 0) affmap[r] = g1 * 256 + g2;
}

// One phase: {ds_read A-quad Q (+ all B if READB) ; STAGE ; VM ;
//             barrier ; lgkmcnt(0) ; setprio(1) 16 MFMA setprio(0) ;
//             barrier}. Q is a literal -> all acc indices compile-time.
#define PHASE(ASB, BSB, Q, READB, STAGE_STMT, VM_STMT)                        \
  {                                                                           \
    if (READB) {                                                              \
      _Pragma("unroll") for (int ni = 0; ni < 4; ++ni) {                      \
        int rc = wcol * 64 + ni * 16 + l16;                                   \
        bfr[ni][0] = *(const bf16x8*)&(BSB)[rc * 64 + (((q) ^ (rc & 7)) * 8)];\
        bfr[ni][1] = *(const bf16x8*)&(BSB)[rc * 64 + (((4 + q) ^ (rc & 7)) * 8)];\
      }                                                                       \
    }                                                                         \
    bf16x8 afq[2][2];                                                         \
    _Pragma("unroll") for (int m2 = 0; m2 < 2; ++m2) {                        \
      int r = wrow * 128 + ((Q) * 2 + m2) * 16 + l16;                         \
      afq[m2][0] = *(const bf16x8*)&(ASB)[r * 64 + (((q) ^ (r & 7)) * 8)];    \
      afq[m2][1] = *(const bf16x8*)&(ASB)[r * 64 + (((4 + q) ^ (r & 7)) * 8)];\
    }                                                                         \
    STAGE_STMT;                                                               \
    VM_STMT;                                                                  \
    __builtin_amdgcn_s_barrier();                                             \
    asm volatile("s_waitcnt lgkmcnt(0)" ::: "memory");                        \
    __builtin_amdgcn_s_setprio(1);                                            \
    _Pragma("unroll") for (int s = 0; s < 2; ++s)                             \
      _Pragma("unroll") for (int m2 = 0; m2 < 2; ++m2)                        \
        _Pragma("unroll") for (int ni = 0; ni < 4; ++ni)                      \
          acc[(Q) * 2 + m2][ni] = __builtin_amdgcn_mfma_f32_16x16x32_bf16(    \
              afq[m2][s], bfr[ni][s], acc[(Q) * 2 + m2][ni], 0, 0, 0);        \
    __builtin_amdgcn_s_setprio(0);                                            \
    __builtin_amdgcn_s_barrier();                                             \
  }

// ---------- gemm256 (R18 8-phase core + R19 affmap epilogue) --------------
// C_z[M,N] = epi(A_z[M,K] @ BT_z[N,K]^T). 256x256 block, 512 thr = 8 waves
// (2 row x 4 col), wave 128x64 (acc[8][4]), BK=64, XOR-swizzled LDS,
// buf0 <-> even K-tiles, buf1 <-> odd K-tiles (64 KiB each, 128 KiB total).
// fuse (fuseW!=0): rs += lrelu(bn(val))*fuseW[col] -> atomicAdd to
//   facc[affmap[r]] if affmap else facc[z*faccStride + r].
__global__ __launch_bounds__(512) void gemm256(
    const bf16* __restrict__ A,
    const bf16* __restrict__ BT,
    bf16* __restrict__ C,
    int K, int N,
    long long batchA, long long batchB, long long batchC,
    const float* __restrict__ scale, const float* __restrict__ offset,
    int lrelu,
    const float* __restrict__ fuseW, float* __restrict__ facc,
    long long faccStride,
    const int* __restrict__ affmap)
{
    __shared__ bf16 As[2 * 256 * 64];   // 64 KiB (buf0|buf1)
    __shared__ bf16 Bs[2 * 256 * 64];   // 64 KiB (buf0|buf1)
    const int tid  = threadIdx.x;
    const int lane = tid & 63;
    const int wave = tid >> 6;
    const int wrow = wave >> 2, wcol = wave & 3;
    const int q = lane >> 4, l16 = lane & 15;
    const int z = blockIdx.z;

    // XCD-aware bijective swizzle (x fastest in dispatch order).
    int bx = blockIdx.x, by = blockIdx.y;
    {
        int nwg = gridDim.x * gridDim.y;
        if (gridDim.z == 1 && (nwg & 7) == 0) {
            int lin = by * gridDim.x + bx;
            int cpx = nwg >> 3;
            int s = (lin & 7) * cpx + (lin >> 3);
            bx = s % gridDim.x;
            by = s / gridDim.x;
        }
    }
    const int row0 = by * 256;
    const int col0 = bx * 256;

    const bf16* Ap = A + (size_t)z * (size_t)batchA;
    const bf16* Bp = BT + (size_t)z * (size_t)batchB;

    f32x4 acc[8][4];
#pragma unroll
    for (int mi = 0; mi < 8; ++mi)
#pragma unroll
        for (int ni = 0; ni < 4; ++ni)
#pragma unroll
            for (int e = 0; e < 4; ++e) acc[mi][ni][e] = 0.f;

    // stage one half-tile (rows h*128..h*128+127) = 2 async loads/thread
    auto stageA2 = [&](int kk, int buf, int h) {
#pragma unroll
        for (int tt = 0; tt < 2; ++tt) {
            int idx = (2 * h + tt) * 512 + tid;
            int r = idx >> 3, sch = idx & 7;
            int gch = sch ^ (r & 7);
            async_load16(Ap + (size_t)(row0 + r) * K + kk + gch * 8,
                         &As[buf * 16384 + idx * 8]);
        }
    };
    auto stageB2 = [&](int kk, int buf, int h) {
#pragma unroll
        for (int tt = 0; tt < 2; ++tt) {
            int idx = (2 * h + tt) * 512 + tid;
            int r = idx >> 3, sch = idx & 7;
            int gch = sch ^ (r & 7);
            async_load16(Bp + (size_t)(col0 + r) * K + kk + gch * 8,
                         &Bs[buf * 16384 + idx * 8]);
        }
    };

    // prologue: tile0 (A+B) -> buf0, tile1 B -> buf1  (6 halves, 12 loads)
    stageA2(0, 0, 0); stageA2(0, 0, 1);
    stageB2(0, 0, 0); stageB2(0, 0, 1);
    stageB2(64, 1, 0); stageB2(64, 1, 1);
    // wait buf0's 8 loads (oldest); buf1.B's 4 stay in flight
    asm volatile("s_waitcnt vmcnt(4)" ::: "memory");
    __builtin_amdgcn_s_barrier();

    bf16x8 bfr[4][2];
    const bf16* A0 = As;          const bf16* B0 = Bs;
    const bf16* A1 = As + 16384;  const bf16* B1 = Bs + 16384;
    const int nt = K >> 6;        // even for all call sites (16 or 4)
    for (int i2 = 0; i2 < nt; i2 += 2) {
        const int kk1 = (i2 + 1) << 6, kk2 = (i2 + 2) << 6,
                  kk3 = (i2 + 3) << 6;
        const bool more = (i2 + 2) < nt;   // tiles i2+2 AND i2+3 exist
        // ---- tile i2 from buf0 (phases 1-4) ----
        PHASE(A0, B0, 0, true,  { stageA2(kk1, 1, 0); }, {});
        PHASE(A0, B0, 1, false, { stageA2(kk1, 1, 1); }, {});
        PHASE(A0, B0, 2, false, { if (more) stageB2(kk2, 0, 0); }, {});
        PHASE(A0, B0, 3, false, { if (more) stageB2(kk2, 0, 1); },
              { if (more)
                    asm volatile("s_waitcnt vmcnt(4)" ::: "memory");
                else
                    asm volatile("s_waitcnt vmcnt(0)" ::: "memory"); });
        // ---- tile i2+1 from buf1 (phases 5-8) ----
        PHASE(A1, B1, 0, true,  { if (more) stageA2(kk2, 0, 0); }, {});
        PHASE(A1, B1, 1, false, { if (more) stageA2(kk2, 0, 1); }, {});
        PHASE(A1, B1, 2, false, { if (more) stageB2(kk3, 1, 0); }, {});
        PHASE(A1, B1, 3, false, { if (more) stageB2(kk3, 1, 1); },
              { if (more)
                    asm volatile("s_waitcnt vmcnt(4)" ::: "memory"); });
    }

    // C/D layout (m89-verified): col = lane&15, row = (lane>>4)*4 + reg
    if (fuseW) {
#pragma unroll
        for (int mi = 0; mi < 8; ++mi)
#pragma unroll
            for (int i = 0; i < 4; ++i) {
                float rs = 0.f;
#pragma unroll
                for (int ni = 0; ni < 4; ++ni) {
                    int cc = col0 + wcol * 64 + ni * 16 + l16;
                    float val = acc[mi][ni][i] * scale[cc] + offset[cc];
                    val = val > 0.f ? val : 0.1f * val;
                    rs += val * fuseW[cc];
                }
                rs += __shfl_xor(rs, 1, 64);
                rs += __shfl_xor(rs, 2, 64);
                rs += __shfl_xor(rs, 4, 64);
                rs += __shfl_xor(rs, 8, 64);
                if (l16 == 0) {
                    int r = row0 + wrow * 128 + mi * 16 + q * 4 + i;
                    float* dst = affmap ? (facc + affmap[r])
                                        : (facc + (size_t)z * faccStride + r);
                    atomicAdd(dst, rs);
                }
            }
        return;
    }
    bf16* Cp = C + (size_t)z * (size_t)batchC;
#pragma unroll
    for (int mi = 0; mi < 8; ++mi)
#pragma unroll
        for (int ni = 0; ni < 4; ++ni)
#pragma unroll
            for (int i = 0; i < 4; ++i) {
                int r = row0 + wrow * 128 + mi * 16 + q * 4 + i;
                int cc = col0 + wcol * 64 + ni * 16 + l16;
                float val = acc[mi][ni][i];
                if (scale) val = val * scale[cc] + offset[cc];
                if (lrelu) val = val > 0.f ? val : 0.1f * val;
                Cp[(size_t)r * N + cc] = (bf16)val;
            }
}

extern "C" void kernel_launch(void* const* d_in, const int* in_sizes, int n_in,
                              void* d_out, int out_size, void* d_ws, size_t ws_size,
                              hipStream_t stream)
{
    const float* f_p   = (const float*)d_in[0];
    const float* f_g   = (const float*)d_in[1];
    const float* bn_g  = (const float*)d_in[2];
    const float* bn_b  = (const float*)d_in[3];
    const float* bn_m  = (const float*)d_in[4];
    const float* bn_v  = (const float*)d_in[5];
    const float* rf_W1 = (const float*)d_in[6];
    const float* rf_b1 = (const float*)d_in[7];
    const float* rf1_g = (const float*)d_in[8];
    const float* rf1_b = (const float*)d_in[9];
    const float* rf1_m = (const float*)d_in[10];
    const float* rf1_v = (const float*)d_in[11];
    const float* rf_W2 = (const float*)d_in[12];
    const float* rf_b2 = (const float*)d_in[13];
    const float* rf2_g = (const float*)d_in[14];
    const float* rf2_b = (const float*)d_in[15];
    const float* rf2_m = (const float*)d_in[16];
    const float* rf2_v = (const float*)d_in[17];
    const float* sfc_W = (const float*)d_in[18];
    const float* sfc_b = (const float*)d_in[19];
    const float* sbn_g = (const float*)d_in[20];
    const float* sbn_b = (const float*)d_in[21];
    const float* sbn_m = (const float*)d_in[22];
    const float* sbn_v = (const float*)d_in[23];
    const float* scl_W = (const float*)d_in[24];
    const float* scl_b = (const float*)d_in[25];
    const float* ffc_W = (const float*)d_in[26];
    const float* ffc_b = (const float*)d_in[27];
    const float* fbn_g = (const float*)d_in[28];
    const float* fbn_b = (const float*)d_in[29];
    const float* fbn_m = (const float*)d_in[30];
    const float* fbn_v = (const float*)d_in[31];
    const float* cls_W = (const float*)d_in[32];
    const float* cls_b = (const float*)d_in[33];

    const size_t MB = 1ull << 20;
    char* ws = (char*)d_ws;
    float* SC      = (float*)(ws);
    float *s0 = SC,        *o0 = SC + 1024;
    float *s1 = SC + 2048, *o1 = SC + 3072;
    float *s2 = SC + 4096, *o2 = SC + 5120;
    float *s3 = SC + 6144, *o3 = SC + 6656;
    float *s4 = SC + 7168, *o4 = SC + 7680;
    float* w_acc   = (float*)(ws + 65536);       // 256 KiB
    float* out_acc = (float*)(ws + 327680);      // 128 KiB
    bf16* wT       = (bf16*)(ws + 458752);       // 128 KiB
    int*  affmap   = (int*)(ws + 589824);        // 139 KiB (34816 ints)
    bf16* W1T      = (bf16*)(ws + 1 * MB);
    bf16* W2T      = (bf16*)(ws + 3 * MB);
    bf16* sfcT     = (bf16*)(ws + 5 * MB);
    bf16* ffcT     = (bf16*)(ws + 6 * MB);

    int nc;
    if      (ws_size >= 170 * MB) nc = 1;        // confirmed since R3
    else if (ws_size >= 90 * MB)  nc = 2;
    else                          nc = 4;
    const int pc = 128 / nc;
    const int R  = pc * 256;
    const size_t hbytes = (size_t)R * 1024 * 2;
    bf16* bufA = (bf16*)(ws + 8 * MB);                    // h
    bf16* bufB = (bf16*)(ws + 8 * MB + hbytes);           // d, then t
    bf16* bufC = (bf16*)(ws + 8 * MB + 2 * hbytes);       // uT [pc][512][256]

    // 1. BN folds (one fused launch; bias=nullptr for segment 0)
    {
        P5All a;
        a.p[0] = { bn_g,  bn_b,  bn_m,  bn_v,  nullptr, s0, o0 };
        a.p[1] = { rf1_g, rf1_b, rf1_m, rf1_v, rf_b1,   s1, o1 };
        a.p[2] = { rf2_g, rf2_b, rf2_m, rf2_v, rf_b2,   s2, o2 };
        a.p[3] = { sbn_g, sbn_b, sbn_m, sbn_v, sfc_b,   s3, o3 };
        a.p[4] = { fbn_g, fbn_b, fbn_m, fbn_v, ffc_b,   s4, o4 };
        prep5_kernel<<<dim3(16), 256, 0, stream>>>(a);
    }

    // 2. weight transposes (f32 -> bf16), LDS-tiled, coalesced both sides
    wtransT_kernel<<<dim3(16, 16), 256, 0, stream>>>(rf_W1, W1T, 1024, 1024);
    wtransT_kernel<<<dim3(16, 16), 256, 0, stream>>>(rf_W2, W2T, 1024, 1024);
    wtransT_kernel<<<dim3(16, 8), 256, 0, stream>>>(sfc_W, sfcT, 1024, 512);
    wtransT_kernel<<<dim3(16, 8), 256, 0, stream>>>(ffc_W, ffcT, 1024, 512);

    // 3. zero accumulators (w_acc + out_acc contiguous)
    hipMemsetAsync(ws + 65536, 0, 393216, stream);

    // 4. symmetric affinity, un-fused: dgc (canonical tile-pairs, bf16)
    //    into probe-phase scratch (dead here), then 8-phase gemm256 with
    //    fused lrelu*bn*scl_W epilogue -> atomicAdd w_acc[affmap[r]].
    {
        bf16* dgc = (bf16*)(ws + 8 * MB);    // up to 71.3 MB (na=1)
        const int na = (ws_size >= 170 * MB) ? 1 : 2;
        const int TP = 136 / na;             // pair-tiles per chunk
        for (int ai = 0; ai < na; ++ai) {
            const int rows = TP * 256;
            dgprep_kernel<<<dim3(rows / 2), 256, 0, stream>>>(
                f_g, s0, o0, dgc, affmap + ai * TP * 256, ai * TP);
            gemm256<<<dim3(2, rows / 256), 512, 0, stream>>>(
                dgc, sfcT, nullptr, 1024, 512,
                0, 0, 0, s3, o3, 1, scl_W, w_acc, 0,
                affmap + ai * TP * 256);
        }
    }
    // 5. wT[g2][g1] = bf16(w[canon] + scl_b)
    wconv_kernel<<<dim3(256), 256, 0, stream>>>(w_acc, scl_b, wT);

    // 6. probe chunks (all gemms 8-phase; d precomputed into bufB)
    for (int ci = 0; ci < nc; ++ci) {
        // d = bn1((f_p - f_g)^2)        [R,1024] bf16 -> bufB (dead after h)
        dprep_kernel<<<dim3(R / 2), 256, 0, stream>>>(
            f_p, f_g, s0, o0, bufB, ci * R);
        // h = lrelu(rf1(d @ W1 + b1))   [R,1024]
        gemm256<<<dim3(4, R / 256), 512, 0, stream>>>(
            bufB, W1T, bufA, 1024, 1024,
            0, 0, 0, s1, o1, 1, nullptr, nullptr, 0, nullptr);
        // t = lrelu(rf2(h @ W2 + b2))   [R,1024] (overwrites d: dead)
        gemm256<<<dim3(4, R / 256), 512, 0, stream>>>(
            bufA, W2T, bufB, 1024, 1024,
            0, 0, 0, s2, o2, 1, nullptr, nullptr, 0, nullptr);
        // uT_p = ffcT @ t_p^T           [pc][512][256]  (batched)
        gemm256<<<dim3(1, 2, pc), 512, 0, stream>>>(
            ffcT, bufB, bufC, 1024, 256,
            0, (long long)256 * 1024, (long long)512 * 256,
            nullptr, nullptr, 0, nullptr, nullptr, 0, nullptr);
        // feat_p = lrelu(fbn(wT @ uT_p^T + b)) . cls_W -> out_acc  (batched)
        gemm256<<<dim3(2, 1, pc), 512, 0, stream>>>(
            wT, bufC, nullptr, 256, 512,
            0, (long long)512 * 256, 0,
            s4, o4, 1, cls_W, out_acc + (size_t)ci * pc * 256, 256, nullptr);
    }
    // 7. d_out = out_acc + cls_b
    finout_kernel<<<dim3(128), 256, 0, stream>>>(out_acc, cls_b, (float*)d_out);
}

// Round 8
// 493.656 us; speedup vs baseline: 1.0601x; 1.0347x over previous
//
#include <hip/hip_runtime.h>

// Sggnn_23218593202512 — round 21: fix the affinity quantization tail.
// R20 budget: affinity gemm = 272 blocks of the 256^2 kernel at 1 block/CU
// (LDS 128KB, 248 regs/wave) -> 1.06 rounds: 16-block round 2 idles 94% of
// the chip for ~50us (effective 456 TF vs 675 elsewhere). Fix: dedicated
// gemm128aff — 128^2 tile, 4 waves, acc[4][4] (64 AGPR, ~140 regs), 64KB
// dbuf LDS -> 2 blocks/CU, 2-phase counted-vmcnt schedule (m228d: the
// measured-best 128^2 quadrant, 622 TF; 128^2+8ph is the documented
// unreproduced quadrant). Grid (4,272)=1088 blocks / 512 slots -> ~94%
// util, 33.5 MFLOP quantum. Epilogue keeps identical 64-col partial-sum
// granularity (8 atomic partials per w_acc entry, same as before) ->
// numerics unchanged. Everything else byte-identical to R20.

typedef __bf16 bf16;
typedef __attribute__((ext_vector_type(8))) __bf16 bf16x8;
typedef __attribute__((ext_vector_type(4))) float f32x4;

#define EPSV 1e-5f

__device__ __forceinline__ void async_load16(const bf16* g, bf16* l) {
    __builtin_amdgcn_global_load_lds(
        (const __attribute__((address_space(1))) void*)g,
        (__attribute__((address_space(3))) void*)l, 16, 0, 0);
}

// 5 BN folds in one launch. Segments: [0,1024)=bn, [1024,2048)=rf1,
// [2048,3072)=rf2, [3072,3584)=sbn, [3584,4096)=fbn.
struct P5 { const float *g, *b, *m, *v, *bias; float *sc, *of; };
struct P5All { P5 p[5]; };
__global__ __launch_bounds__(256) void prep5_kernel(P5All a)
{
    int i = blockIdx.x * 256 + threadIdx.x;
    int seg, off;
    if      (i < 1024) { seg = 0; off = i; }
    else if (i < 2048) { seg = 1; off = i - 1024; }
    else if (i < 3072) { seg = 2; off = i - 2048; }
    else if (i < 3584) { seg = 3; off = i - 3072; }
    else               { seg = 4; off = i - 3584; }
    const P5& q = a.p[seg];
    float s = q.g[off] / sqrtf(q.v[off] + EPSV);
    float o = q.b[off] - q.m[off] * s;
    if (q.bias) o += q.bias[off] * s;
    q.sc[off] = s;
    q.of[off] = o;
}

// LDS-tiled transpose: out[n*K+k] = bf16(in[k*N+n]). 64x64 f32 tile,
// +1-pad (65) -> conflict-free; both global access sides coalesced.
// Grid: (K/64, N/64).
__global__ __launch_bounds__(256) void wtransT_kernel(
    const float* __restrict__ in, bf16* __restrict__ out, int K, int N)
{
    __shared__ float tile[64][65];
    const int k0 = blockIdx.x * 64, n0 = blockIdx.y * 64;
    const int c = threadIdx.x & 63, r4 = threadIdx.x >> 6;
#pragma unroll
    for (int i = 0; i < 16; ++i) {
        int r = r4 * 16 + i;
        tile[r][c] = in[(size_t)(k0 + r) * N + n0 + c];
    }
    __syncthreads();
#pragma unroll
    for (int i = 0; i < 16; ++i) {
        int r = r4 * 16 + i;
        out[(size_t)(n0 + r) * K + k0 + c] = (bf16)tile[c][r];
    }
}

// wT[g2*256+g1] = bf16(w[g1][g2] + scl_b); only g-tiles ta<=tb computed,
// mirror otherwise (w symmetric). [R11/R12-verified]
__global__ __launch_bounds__(256) void wconv_kernel(
    const float* __restrict__ w_acc, const float* __restrict__ sclb,
    bf16* __restrict__ wT)
{
    int tid = blockIdx.x * 256 + threadIdx.x;
    int g2 = tid >> 8, g1 = tid & 255;
    int idx = ((g1 >> 4) <= (g2 >> 4)) ? (g1 * 256 + g2) : (g2 * 256 + g1);
    wT[tid] = (bf16)(w_acc[idx] + sclb[0]);
}

__global__ __launch_bounds__(256) void finout_kernel(
    const float* __restrict__ acc, const float* __restrict__ clsb,
    float* __restrict__ out)
{
    int i = blockIdx.x * 256 + threadIdx.x;
    out[i] = acc[i] + clsb[0];
}

// d[r][k] = bf16((f_p[gr>>8][k] - f_g[gr&255][k])^2 * ps[k] + po[k]),
// gr = rowOff + r. One bf16x8 per thread; writes coalesced 16B.
__global__ __launch_bounds__(256) void dprep_kernel(
    const float* __restrict__ X, const float* __restrict__ Y,
    const float* __restrict__ ps, const float* __restrict__ po,
    bf16* __restrict__ d, int rowOff)
{
    int t  = blockIdx.x * 256 + threadIdx.x;
    int k0 = (t & 127) * 8;           // 128 threads span one 1024-wide row
    int r  = t >> 7;
    int gr = rowOff + r;
    const float* xp = X + (size_t)(gr >> 8) * 1024 + k0;
    const float* yp = Y + (size_t)(gr & 255) * 1024 + k0;
    f32x4 x0 = *(const f32x4*)xp, x1 = *(const f32x4*)(xp + 4);
    f32x4 y0 = *(const f32x4*)yp, y1 = *(const f32x4*)(yp + 4);
    f32x4 sa = *(const f32x4*)(ps + k0), sb = *(const f32x4*)(ps + k0 + 4);
    f32x4 oa = *(const f32x4*)(po + k0), ob = *(const f32x4*)(po + k0 + 4);
    bf16x8 dv;
#pragma unroll
    for (int j = 0; j < 4; ++j) {
        float d0 = x0[j] - y0[j];
        float d1 = x1[j] - y1[j];
        dv[j]     = (bf16)(d0 * d0 * sa[j] + oa[j]);
        dv[j + 4] = (bf16)(d1 * d1 * sb[j] + ob[j]);
    }
    *(bf16x8*)&d[(size_t)r * 1024 + k0] = dv;
}

// dg for canonical gallery tile-pairs. Local row r of this chunk maps to
// pair-tile p = tileOff + (r>>8) -> triangular (ta,tb); rr = r&255:
// g1 = ta*16 + (rr>>4), g2 = tb*16 + (rr&15). Writes dg[r][k] bf16 and
// affmap[r] = g1*256+g2.
__global__ __launch_bounds__(256) void dgprep_kernel(
    const float* __restrict__ X,
    const float* __restrict__ ps, const float* __restrict__ po,
    bf16* __restrict__ dg, int* __restrict__ affmap, int tileOff)
{
    int t  = blockIdx.x * 256 + threadIdx.x;
    int k0 = (t & 127) * 8;
    int r  = t >> 7;
    int p  = tileOff + (r >> 8);
    int ta = 0, rem = p;
    while (rem >= 16 - ta) { rem -= 16 - ta; ++ta; }
    int tb = ta + rem;
    int rr = r & 255;
    int g1 = ta * 16 + (rr >> 4), g2 = tb * 16 + (rr & 15);
    const float* xp = X + (size_t)g1 * 1024 + k0;
    const float* yp = X + (size_t)g2 * 1024 + k0;
    f32x4 x0 = *(const f32x4*)xp, x1 = *(const f32x4*)(xp + 4);
    f32x4 y0 = *(const f32x4*)yp, y1 = *(const f32x4*)(yp + 4);
    f32x4 sa = *(const f32x4*)(ps + k0), sb = *(const f32x4*)(ps + k0 + 4);
    f32x4 oa = *(const f32x4*)(po + k0), ob = *(const f32x4*)(po + k0 + 4);
    bf16x8 dv;
#pragma unroll
    for (int j = 0; j < 4; ++j) {
        float d0 = x0[j] - y0[j];
        float d1 = x1[j] - y1[j];
        dv[j]     = (bf16)(d0 * d0 * sa[j] + oa[j]);
        dv[j + 4] = (bf16)(d1 * d1 * sb[j] + ob[j]);
    }
    *(bf16x8*)&dg[(size_t)r * 1024 + k0] = dv;
    if (k0 == 0) affmap[r] = g1 * 256 + g2;
}

// ---------- gemm128aff (R21): affinity gemm, 128^2 / 2 blocks/CU ----------
// w-partials = lrelu(bn(dgc @ sfcT^T)) . sclW -> atomicAdd w_acc[affmap[r]].
// 128x128 tile, 256 thr = 4 waves (2x2), wave 64x64 (acc[4][4]), BK=64,
// XOR-swizzled LDS, 2x(16+16)KB = 64KB double buffer -> 2 blocks/CU.
// 2-phase counted-vmcnt schedule (R17-proven; m228d-best for 128^2):
// stage(t+1) [8 loads] -> vmcnt(8)+s_barrier -> ds_read+32 MFMA ->
// s_barrier. Cross-block overlap (2 resident) covers the drains (m114).
__global__ __launch_bounds__(256) void gemm128aff(
    const bf16* __restrict__ A,       // dgc [rows][K]
    const bf16* __restrict__ BT,      // sfcT [512][K]
    int K,
    const float* __restrict__ scale, const float* __restrict__ offset,
    const float* __restrict__ sclW, float* __restrict__ w_acc,
    const int* __restrict__ affmap)
{
    __shared__ bf16 As[2 * 128 * 64];   // 32 KiB
    __shared__ bf16 Bs[2 * 128 * 64];   // 32 KiB
    const int tid  = threadIdx.x;
    const int lane = tid & 63;
    const int wave = tid >> 6;
    const int wrow = wave >> 1, wcol = wave & 1;
    const int q = lane >> 4, l16 = lane & 15;

    // XCD-aware bijective swizzle (nwg = 1088, %8 == 0)
    int bx = blockIdx.x, by = blockIdx.y;
    {
        int nwg = gridDim.x * gridDim.y;
        if ((nwg & 7) == 0) {
            int lin = by * gridDim.x + bx;
            int cpx = nwg >> 3;
            int s = (lin & 7) * cpx + (lin >> 3);
            bx = s % gridDim.x;
            by = s / gridDim.x;
        }
    }
    const int row0 = by * 128;
    const int col0 = bx * 128;

    f32x4 acc[4][4];
#pragma unroll
    for (int mi = 0; mi < 4; ++mi)
#pragma unroll
        for (int ni = 0; ni < 4; ++ni)
#pragma unroll
            for (int e = 0; e < 4; ++e) acc[mi][ni][e] = 0.f;

    auto stageA = [&](int kk, bf16* dst) {
#pragma unroll
        for (int t = 0; t < 4; ++t) {
            int idx = t * 256 + tid;            // 1024 chunks (128 rows x 8)
            int r = idx >> 3, sch = idx & 7;
            int gch = sch ^ (r & 7);
            async_load16(A + (size_t)(row0 + r) * K + kk + gch * 8,
                         &dst[idx * 8]);
        }
    };
    auto stageB = [&](int kk, bf16* dst) {
#pragma unroll
        for (int t = 0; t < 4; ++t) {
            int idx = t * 256 + tid;
            int r = idx >> 3, sch = idx & 7;
            int gch = sch ^ (r & 7);
            async_load16(BT + (size_t)(col0 + r) * K + kk + gch * 8,
                         &dst[idx * 8]);
        }
    };

    stageA(0, As);
    stageB(0, Bs);

    int cur = 0;
    const int nt = K >> 6;
    for (int t = 0; t < nt; ++t) {
        const bool pf = (t + 1) < nt;
        if (pf) {
            stageA((t + 1) * 64, As + (cur ^ 1) * 8192);
            stageB((t + 1) * 64, Bs + (cur ^ 1) * 8192);
        }
        if (pf) {
            asm volatile("s_waitcnt vmcnt(8)\n\ts_barrier" ::: "memory");
        } else {
            asm volatile("s_waitcnt vmcnt(0) lgkmcnt(0)\n\ts_barrier"
                         ::: "memory");
        }
        const bf16* Asb = As + cur * 8192;
        const bf16* Bsb = Bs + cur * 8192;
#pragma unroll
        for (int s = 0; s < 2; ++s) {
            bf16x8 af[4], bfr[4];
#pragma unroll
            for (int mi = 0; mi < 4; ++mi) {
                int r = wrow * 64 + mi * 16 + l16;
                af[mi] = *(const bf16x8*)&Asb[r * 64 + (((s * 4 + q) ^ (r & 7)) * 8)];
            }
#pragma unroll
            for (int ni = 0; ni < 4; ++ni) {
                int rc = wcol * 64 + ni * 16 + l16;
                bfr[ni] = *(const bf16x8*)&Bsb[rc * 64 + (((s * 4 + q) ^ (rc & 7)) * 8)];
            }
#pragma unroll
            for (int mi = 0; mi < 4; ++mi)
#pragma unroll
                for (int ni = 0; ni < 4; ++ni)
                    acc[mi][ni] = __builtin_amdgcn_mfma_f32_16x16x32_bf16(
                        af[mi], bfr[ni], acc[mi][ni], 0, 0, 0);
        }
        if (pf) asm volatile("s_barrier" ::: "memory");
        cur ^= 1;
    }

    // fused epilogue: identical 64-col partial granularity to the 256^2
    // version (8 atomic partials per w_acc entry). C/D layout m89.
#pragma unroll
    for (int mi = 0; mi < 4; ++mi)
#pragma unroll
        for (int i = 0; i < 4; ++i) {
            float rs = 0.f;
#pragma unroll
            for (int ni = 0; ni < 4; ++ni) {
                int cc = col0 + wcol * 64 + ni * 16 + l16;
                float val = acc[mi][ni][i] * scale[cc] + offset[cc];
                val = val > 0.f ? val : 0.1f * val;
                rs += val * sclW[cc];
            }
            rs += __shfl_xor(rs, 1, 64);
            rs += __shfl_xor(rs, 2, 64);
            rs += __shfl_xor(rs, 4, 64);
            rs += __shfl_xor(rs, 8, 64);
            if (l16 == 0) {
                int r = row0 + wrow * 64 + mi * 16 + q * 4 + i;
                atomicAdd(w_acc + affmap[r], rs);
            }
        }
}

// One phase: {ds_read A-quad Q (+ all B if READB) ; STAGE ; VM ;
//             barrier ; lgkmcnt(0) ; setprio(1) 16 MFMA setprio(0) ;
//             barrier}. Q is a literal -> all acc indices compile-time.
#define PHASE(ASB, BSB, Q, READB, STAGE_STMT, VM_STMT)                        \
  {                                                                           \
    if (READB) {                                                              \
      _Pragma("unroll") for (int ni = 0; ni < 4; ++ni) {                      \
        int rc = wcol * 64 + ni * 16 + l16;                                   \
        bfr[ni][0] = *(const bf16x8*)&(BSB)[rc * 64 + (((q) ^ (rc & 7)) * 8)];\
        bfr[ni][1] = *(const bf16x8*)&(BSB)[rc * 64 + (((4 + q) ^ (rc & 7)) * 8)];\
      }                                                                       \
    }                                                                         \
    bf16x8 afq[2][2];                                                         \
    _Pragma("unroll") for (int m2 = 0; m2 < 2; ++m2) {                        \
      int r = wrow * 128 + ((Q) * 2 + m2) * 16 + l16;                         \
      afq[m2][0] = *(const bf16x8*)&(ASB)[r * 64 + (((q) ^ (r & 7)) * 8)];    \
      afq[m2][1] = *(const bf16x8*)&(ASB)[r * 64 + (((4 + q) ^ (r & 7)) * 8)];\
    }                                                                         \
    STAGE_STMT;                                                               \
    VM_STMT;                                                                  \
    __builtin_amdgcn_s_barrier();                                             \
    asm volatile("s_waitcnt lgkmcnt(0)" ::: "memory");                        \
    __builtin_amdgcn_s_setprio(1);                                            \
    _Pragma("unroll") for (int s = 0; s < 2; ++s)                             \
      _Pragma("unroll") for (int m2 = 0; m2 < 2; ++m2)                        \
        _Pragma("unroll") for (int ni = 0; ni < 4; ++ni)                      \
          acc[(Q) * 2 + m2][ni] = __builtin_amdgcn_mfma_f32_16x16x32_bf16(    \
              afq[m2][s], bfr[ni][s], acc[(Q) * 2 + m2][ni], 0, 0, 0);        \
    __builtin_amdgcn_s_setprio(0);                                            \
    __builtin_amdgcn_s_barrier();                                             \
  }

// ---------- gemm256 (R18 8-phase core + R19 affmap epilogue) --------------
// C_z[M,N] = epi(A_z[M,K] @ BT_z[N,K]^T). 256x256 block, 512 thr = 8 waves
// (2 row x 4 col), wave 128x64 (acc[8][4]), BK=64, XOR-swizzled LDS,
// buf0 <-> even K-tiles, buf1 <-> odd K-tiles (64 KiB each, 128 KiB total).
// fuse (fuseW!=0): rs += lrelu(bn(val))*fuseW[col] -> atomicAdd to
//   facc[affmap[r]] if affmap else facc[z*faccStride + r].
__global__ __launch_bounds__(512) void gemm256(
    const bf16* __restrict__ A,
    const bf16* __restrict__ BT,
    bf16* __restrict__ C,
    int K, int N,
    long long batchA, long long batchB, long long batchC,
    const float* __restrict__ scale, const float* __restrict__ offset,
    int lrelu,
    const float* __restrict__ fuseW, float* __restrict__ facc,
    long long faccStride,
    const int* __restrict__ affmap)
{
    __shared__ bf16 As[2 * 256 * 64];   // 64 KiB (buf0|buf1)
    __shared__ bf16 Bs[2 * 256 * 64];   // 64 KiB (buf0|buf1)
    const int tid  = threadIdx.x;
    const int lane = tid & 63;
    const int wave = tid >> 6;
    const int wrow = wave >> 2, wcol = wave & 3;
    const int q = lane >> 4, l16 = lane & 15;
    const int z = blockIdx.z;

    // XCD-aware bijective swizzle (x fastest in dispatch order).
    int bx = blockIdx.x, by = blockIdx.y;
    {
        int nwg = gridDim.x * gridDim.y;
        if (gridDim.z == 1 && (nwg & 7) == 0) {
            int lin = by * gridDim.x + bx;
            int cpx = nwg >> 3;
            int s = (lin & 7) * cpx + (lin >> 3);
            bx = s % gridDim.x;
            by = s / gridDim.x;
        }
    }
    const int row0 = by * 256;
    const int col0 = bx * 256;

    const bf16* Ap = A + (size_t)z * (size_t)batchA;
    const bf16* Bp = BT + (size_t)z * (size_t)batchB;

    f32x4 acc[8][4];
#pragma unroll
    for (int mi = 0; mi < 8; ++mi)
#pragma unroll
        for (int ni = 0; ni < 4; ++ni)
#pragma unroll
            for (int e = 0; e < 4; ++e) acc[mi][ni][e] = 0.f;

    // stage one half-tile (rows h*128..h*128+127) = 2 async loads/thread
    auto stageA2 = [&](int kk, int buf, int h) {
#pragma unroll
        for (int tt = 0; tt < 2; ++tt) {
            int idx = (2 * h + tt) * 512 + tid;
            int r = idx >> 3, sch = idx & 7;
            int gch = sch ^ (r & 7);
            async_load16(Ap + (size_t)(row0 + r) * K + kk + gch * 8,
                         &As[buf * 16384 + idx * 8]);
        }
    };
    auto stageB2 = [&](int kk, int buf, int h) {
#pragma unroll
        for (int tt = 0; tt < 2; ++tt) {
            int idx = (2 * h + tt) * 512 + tid;
            int r = idx >> 3, sch = idx & 7;
            int gch = sch ^ (r & 7);
            async_load16(Bp + (size_t)(col0 + r) * K + kk + gch * 8,
                         &Bs[buf * 16384 + idx * 8]);
        }
    };

    // prologue: tile0 (A+B) -> buf0, tile1 B -> buf1  (6 halves, 12 loads)
    stageA2(0, 0, 0); stageA2(0, 0, 1);
    stageB2(0, 0, 0); stageB2(0, 0, 1);
    stageB2(64, 1, 0); stageB2(64, 1, 1);
    // wait buf0's 8 loads (oldest); buf1.B's 4 stay in flight
    asm volatile("s_waitcnt vmcnt(4)" ::: "memory");
    __builtin_amdgcn_s_barrier();

    bf16x8 bfr[4][2];
    const bf16* A0 = As;          const bf16* B0 = Bs;
    const bf16* A1 = As + 16384;  const bf16* B1 = Bs + 16384;
    const int nt = K >> 6;        // even for all call sites (16 or 4)
    for (int i2 = 0; i2 < nt; i2 += 2) {
        const int kk1 = (i2 + 1) << 6, kk2 = (i2 + 2) << 6,
                  kk3 = (i2 + 3) << 6;
        const bool more = (i2 + 2) < nt;   // tiles i2+2 AND i2+3 exist
        // ---- tile i2 from buf0 (phases 1-4) ----
        PHASE(A0, B0, 0, true,  { stageA2(kk1, 1, 0); }, {});
        PHASE(A0, B0, 1, false, { stageA2(kk1, 1, 1); }, {});
        PHASE(A0, B0, 2, false, { if (more) stageB2(kk2, 0, 0); }, {});
        PHASE(A0, B0, 3, false, { if (more) stageB2(kk2, 0, 1); },
              { if (more)
                    asm volatile("s_waitcnt vmcnt(4)" ::: "memory");
                else
                    asm volatile("s_waitcnt vmcnt(0)" ::: "memory"); });
        // ---- tile i2+1 from buf1 (phases 5-8) ----
        PHASE(A1, B1, 0, true,  { if (more) stageA2(kk2, 0, 0); }, {});
        PHASE(A1, B1, 1, false, { if (more) stageA2(kk2, 0, 1); }, {});
        PHASE(A1, B1, 2, false, { if (more) stageB2(kk3, 1, 0); }, {});
        PHASE(A1, B1, 3, false, { if (more) stageB2(kk3, 1, 1); },
              { if (more)
                    asm volatile("s_waitcnt vmcnt(4)" ::: "memory"); });
    }

    // C/D layout (m89-verified): col = lane&15, row = (lane>>4)*4 + reg
    if (fuseW) {
#pragma unroll
        for (int mi = 0; mi < 8; ++mi)
#pragma unroll
            for (int i = 0; i < 4; ++i) {
                float rs = 0.f;
#pragma unroll
                for (int ni = 0; ni < 4; ++ni) {
                    int cc = col0 + wcol * 64 + ni * 16 + l16;
                    float val = acc[mi][ni][i] * scale[cc] + offset[cc];
                    val = val > 0.f ? val : 0.1f * val;
                    rs += val * fuseW[cc];
                }
                rs += __shfl_xor(rs, 1, 64);
                rs += __shfl_xor(rs, 2, 64);
                rs += __shfl_xor(rs, 4, 64);
                rs += __shfl_xor(rs, 8, 64);
                if (l16 == 0) {
                    int r = row0 + wrow * 128 + mi * 16 + q * 4 + i;
                    float* dst = affmap ? (facc + affmap[r])
                                        : (facc + (size_t)z * faccStride + r);
                    atomicAdd(dst, rs);
                }
            }
        return;
    }
    bf16* Cp = C + (size_t)z * (size_t)batchC;
#pragma unroll
    for (int mi = 0; mi < 8; ++mi)
#pragma unroll
        for (int ni = 0; ni < 4; ++ni)
#pragma unroll
            for (int i = 0; i < 4; ++i) {
                int r = row0 + wrow * 128 + mi * 16 + q * 4 + i;
                int cc = col0 + wcol * 64 + ni * 16 + l16;
                float val = acc[mi][ni][i];
                if (scale) val = val * scale[cc] + offset[cc];
                if (lrelu) val = val > 0.f ? val : 0.1f * val;
                Cp[(size_t)r * N + cc] = (bf16)val;
            }
}

extern "C" void kernel_launch(void* const* d_in, const int* in_sizes, int n_in,
                              void* d_out, int out_size, void* d_ws, size_t ws_size,
                              hipStream_t stream)
{
    const float* f_p   = (const float*)d_in[0];
    const float* f_g   = (const float*)d_in[1];
    const float* bn_g  = (const float*)d_in[2];
    const float* bn_b  = (const float*)d_in[3];
    const float* bn_m  = (const float*)d_in[4];
    const float* bn_v  = (const float*)d_in[5];
    const float* rf_W1 = (const float*)d_in[6];
    const float* rf_b1 = (const float*)d_in[7];
    const float* rf1_g = (const float*)d_in[8];
    const float* rf1_b = (const float*)d_in[9];
    const float* rf1_m = (const float*)d_in[10];
    const float* rf1_v = (const float*)d_in[11];
    const float* rf_W2 = (const float*)d_in[12];
    const float* rf_b2 = (const float*)d_in[13];
    const float* rf2_g = (const float*)d_in[14];
    const float* rf2_b = (const float*)d_in[15];
    const float* rf2_m = (const float*)d_in[16];
    const float* rf2_v = (const float*)d_in[17];
    const float* sfc_W = (const float*)d_in[18];
    const float* sfc_b = (const float*)d_in[19];
    const float* sbn_g = (const float*)d_in[20];
    const float* sbn_b = (const float*)d_in[21];
    const float* sbn_m = (const float*)d_in[22];
    const float* sbn_v = (const float*)d_in[23];
    const float* scl_W = (const float*)d_in[24];
    const float* scl_b = (const float*)d_in[25];
    const float* ffc_W = (const float*)d_in[26];
    const float* ffc_b = (const float*)d_in[27];
    const float* fbn_g = (const float*)d_in[28];
    const float* fbn_b = (const float*)d_in[29];
    const float* fbn_m = (const float*)d_in[30];
    const float* fbn_v = (const float*)d_in[31];
    const float* cls_W = (const float*)d_in[32];
    const float* cls_b = (const float*)d_in[33];

    const size_t MB = 1ull << 20;
    char* ws = (char*)d_ws;
    float* SC      = (float*)(ws);
    float *s0 = SC,        *o0 = SC + 1024;
    float *s1 = SC + 2048, *o1 = SC + 3072;
    float *s2 = SC + 4096, *o2 = SC + 5120;
    float *s3 = SC + 6144, *o3 = SC + 6656;
    float *s4 = SC + 7168, *o4 = SC + 7680;
    float* w_acc   = (float*)(ws + 65536);       // 256 KiB
    float* out_acc = (float*)(ws + 327680);      // 128 KiB
    bf16* wT       = (bf16*)(ws + 458752);       // 128 KiB
    int*  affmap   = (int*)(ws + 589824);        // 139 KiB (34816 ints)
    bf16* W1T      = (bf16*)(ws + 1 * MB);
    bf16* W2T      = (bf16*)(ws + 3 * MB);
    bf16* sfcT     = (bf16*)(ws + 5 * MB);
    bf16* ffcT     = (bf16*)(ws + 6 * MB);

    int nc;
    if      (ws_size >= 170 * MB) nc = 1;        // confirmed since R3
    else if (ws_size >= 90 * MB)  nc = 2;
    else                          nc = 4;
    const int pc = 128 / nc;
    const int R  = pc * 256;
    const size_t hbytes = (size_t)R * 1024 * 2;
    bf16* bufA = (bf16*)(ws + 8 * MB);                    // h
    bf16* bufB = (bf16*)(ws + 8 * MB + hbytes);           // d, then t
    bf16* bufC = (bf16*)(ws + 8 * MB + 2 * hbytes);       // uT [pc][512][256]

    // 1. BN folds (one fused launch; bias=nullptr for segment 0)
    {
        P5All a;
        a.p[0] = { bn_g,  bn_b,  bn_m,  bn_v,  nullptr, s0, o0 };
        a.p[1] = { rf1_g, rf1_b, rf1_m, rf1_v, rf_b1,   s1, o1 };
        a.p[2] = { rf2_g, rf2_b, rf2_m, rf2_v, rf_b2,   s2, o2 };
        a.p[3] = { sbn_g, sbn_b, sbn_m, sbn_v, sfc_b,   s3, o3 };
        a.p[4] = { fbn_g, fbn_b, fbn_m, fbn_v, ffc_b,   s4, o4 };
        prep5_kernel<<<dim3(16), 256, 0, stream>>>(a);
    }

    // 2. weight transposes (f32 -> bf16), LDS-tiled, coalesced both sides
    wtransT_kernel<<<dim3(16, 16), 256, 0, stream>>>(rf_W1, W1T, 1024, 1024);
    wtransT_kernel<<<dim3(16, 16), 256, 0, stream>>>(rf_W2, W2T, 1024, 1024);
    wtransT_kernel<<<dim3(16, 8), 256, 0, stream>>>(sfc_W, sfcT, 1024, 512);
    wtransT_kernel<<<dim3(16, 8), 256, 0, stream>>>(ffc_W, ffcT, 1024, 512);

    // 3. zero accumulators (w_acc + out_acc contiguous)
    hipMemsetAsync(ws + 65536, 0, 393216, stream);

    // 4. symmetric affinity, un-fused: dgprep materializes dgc, then the
    //    2-blocks/CU 128^2 gemm (grid (4,272)=1088 blocks, ~94% util vs
    //    272-block 256^2 = 1.06 rounds) -> atomicAdd w_acc[affmap[r]].
    {
        bf16* dgc = (bf16*)(ws + 8 * MB);    // up to 71.3 MB (na=1)
        const int na = (ws_size >= 170 * MB) ? 1 : 2;
        const int TP = 136 / na;             // pair-tiles per chunk
        for (int ai = 0; ai < na; ++ai) {
            const int rows = TP * 256;
            dgprep_kernel<<<dim3(rows / 2), 256, 0, stream>>>(
                f_g, s0, o0, dgc, affmap + ai * TP * 256, ai * TP);
            gemm128aff<<<dim3(4, rows / 128), 256, 0, stream>>>(
                dgc, sfcT, 1024, s3, o3, scl_W, w_acc,
                affmap + ai * TP * 256);
        }
    }
    // 5. wT[g2][g1] = bf16(w[canon] + scl_b)
    wconv_kernel<<<dim3(256), 256, 0, stream>>>(w_acc, scl_b, wT);

    // 6. probe chunks (all gemms 8-phase; d precomputed into bufB)
    for (int ci = 0; ci < nc; ++ci) {
        // d = bn1((f_p - f_g)^2)        [R,1024] bf16 -> bufB (dead after h)
        dprep_kernel<<<dim3(R / 2), 256, 0, stream>>>(
            f_p, f_g, s0, o0, bufB, ci * R);
        // h = lrelu(rf1(d @ W1 + b1))   [R,1024]
        gemm256<<<dim3(4, R / 256), 512, 0, stream>>>(
            bufB, W1T, bufA, 1024, 1024,
            0, 0, 0, s1, o1, 1, nullptr, nullptr, 0, nullptr);
        // t = lrelu(rf2(h @ W2 + b2))   [R,1024] (overwrites d: dead)
        gemm256<<<dim3(4, R / 256), 512, 0, stream>>>(
            bufA, W2T, bufB, 1024, 1024,
            0, 0, 0, s2, o2, 1, nullptr, nullptr, 0, nullptr);
        // uT_p = ffcT @ t_p^T           [pc][512][256]  (batched)
        gemm256<<<dim3(1, 2, pc), 512, 0, stream>>>(
            ffcT, bufB, bufC, 1024, 256,
            0, (long long)256 * 1024, (long long)512 * 256,
            nullptr, nullptr, 0, nullptr, nullptr, 0, nullptr);
        // feat_p = lrelu(fbn(wT @ uT_p^T + b)) . cls_W -> out_acc  (batched)
        gemm256<<<dim3(2, 1, pc), 512, 0, stream>>>(
            wT, bufC, nullptr, 256, 512,
            0, (long long)512 * 256, 0,
            s4, o4, 1, cls_W, out_acc + (size_t)ci * pc * 256, 256, nullptr);
    }
    // 7. d_out = out_acc + cls_b
    finout_kernel<<<dim3(128), 256, 0, stream>>>(out_acc, cls_b, (float*)d_out);
}

// Round 9
// 484.029 us; speedup vs baseline: 1.0812x; 1.0199x over previous
//
#include <hip/hip_runtime.h>

// Sggnn_23218593202512 — round 22: (A) remove the redundant lgkmcnt(0)
// full-drain in PHASE — ds_reads are C++ loads, the compiler already emits
// counted lgkmcnt before each dependent MFMA, so the explicit drain forced
// ~12 LDS reads to complete before the FIRST MFMA of every phase instead
// of overlapping. WAR safety: each phase's reads are fully consumed by its
// own MFMA cluster (RAW waits) before the phase-end barrier, and restaging
// of the same buffer happens >= 2 barriers later; staging visibility is
// vmcnt-side (unchanged). (B) 4 wtrans launches -> 1 (job table, grid.z).
// (C) feat atomics go directly to d_out (zeroed by memset), cls_b added by
// the single (col0==0 && wcol==0) contributor -> finout/out_acc deleted.
// gemm core otherwise byte-identical; gemm128aff/dprep/dgprep untouched.

typedef __bf16 bf16;
typedef __attribute__((ext_vector_type(8))) __bf16 bf16x8;
typedef __attribute__((ext_vector_type(4))) float f32x4;

#define EPSV 1e-5f

__device__ __forceinline__ void async_load16(const bf16* g, bf16* l) {
    __builtin_amdgcn_global_load_lds(
        (const __attribute__((address_space(1))) void*)g,
        (__attribute__((address_space(3))) void*)l, 16, 0, 0);
}

// 5 BN folds in one launch. Segments: [0,1024)=bn, [1024,2048)=rf1,
// [2048,3072)=rf2, [3072,3584)=sbn, [3584,4096)=fbn.
struct P5 { const float *g, *b, *m, *v, *bias; float *sc, *of; };
struct P5All { P5 p[5]; };
__global__ __launch_bounds__(256) void prep5_kernel(P5All a)
{
    int i = blockIdx.x * 256 + threadIdx.x;
    int seg, off;
    if      (i < 1024) { seg = 0; off = i; }
    else if (i < 2048) { seg = 1; off = i - 1024; }
    else if (i < 3072) { seg = 2; off = i - 2048; }
    else if (i < 3584) { seg = 3; off = i - 3072; }
    else               { seg = 4; off = i - 3584; }
    const P5& q = a.p[seg];
    float s = q.g[off] / sqrtf(q.v[off] + EPSV);
    float o = q.b[off] - q.m[off] * s;
    if (q.bias) o += q.bias[off] * s;
    q.sc[off] = s;
    q.of[off] = o;
}

// LDS-tiled transpose, 4 jobs in one launch (grid.z = job).
// out[n*K+k] = bf16(in[k*N+n]); 64x64 f32 tile, +1 pad, both sides
// coalesced. Jobs with N=512 idle half their y-blocks (early return).
struct TJob { const float* in; bf16* out; int K, N; };
struct TJobs { TJob j[4]; };
__global__ __launch_bounds__(256) void wtrans4_kernel(TJobs a)
{
    const TJob& jb = a.j[blockIdx.z];
    const int k0 = blockIdx.x * 64, n0 = blockIdx.y * 64;
    if (n0 >= jb.N || k0 >= jb.K) return;
    __shared__ float tile[64][65];
    const int c = threadIdx.x & 63, r4 = threadIdx.x >> 6;
#pragma unroll
    for (int i = 0; i < 16; ++i) {
        int r = r4 * 16 + i;
        tile[r][c] = jb.in[(size_t)(k0 + r) * jb.N + n0 + c];
    }
    __syncthreads();
#pragma unroll
    for (int i = 0; i < 16; ++i) {
        int r = r4 * 16 + i;
        jb.out[(size_t)(n0 + r) * jb.K + k0 + c] = (bf16)tile[c][r];
    }
}

// wT[g2*256+g1] = bf16(w[g1][g2] + scl_b); only g-tiles ta<=tb computed,
// mirror otherwise (w symmetric). [R11/R12-verified]
__global__ __launch_bounds__(256) void wconv_kernel(
    const float* __restrict__ w_acc, const float* __restrict__ sclb,
    bf16* __restrict__ wT)
{
    int tid = blockIdx.x * 256 + threadIdx.x;
    int g2 = tid >> 8, g1 = tid & 255;
    int idx = ((g1 >> 4) <= (g2 >> 4)) ? (g1 * 256 + g2) : (g2 * 256 + g1);
    wT[tid] = (bf16)(w_acc[idx] + sclb[0]);
}

// d[r][k] = bf16((f_p[gr>>8][k] - f_g[gr&255][k])^2 * ps[k] + po[k]),
// gr = rowOff + r. One bf16x8 per thread; writes coalesced 16B.
__global__ __launch_bounds__(256) void dprep_kernel(
    const float* __restrict__ X, const float* __restrict__ Y,
    const float* __restrict__ ps, const float* __restrict__ po,
    bf16* __restrict__ d, int rowOff)
{
    int t  = blockIdx.x * 256 + threadIdx.x;
    int k0 = (t & 127) * 8;           // 128 threads span one 1024-wide row
    int r  = t >> 7;
    int gr = rowOff + r;
    const float* xp = X + (size_t)(gr >> 8) * 1024 + k0;
    const float* yp = Y + (size_t)(gr & 255) * 1024 + k0;
    f32x4 x0 = *(const f32x4*)xp, x1 = *(const f32x4*)(xp + 4);
    f32x4 y0 = *(const f32x4*)yp, y1 = *(const f32x4*)(yp + 4);
    f32x4 sa = *(const f32x4*)(ps + k0), sb = *(const f32x4*)(ps + k0 + 4);
    f32x4 oa = *(const f32x4*)(po + k0), ob = *(const f32x4*)(po + k0 + 4);
    bf16x8 dv;
#pragma unroll
    for (int j = 0; j < 4; ++j) {
        float d0 = x0[j] - y0[j];
        float d1 = x1[j] - y1[j];
        dv[j]     = (bf16)(d0 * d0 * sa[j] + oa[j]);
        dv[j + 4] = (bf16)(d1 * d1 * sb[j] + ob[j]);
    }
    *(bf16x8*)&d[(size_t)r * 1024 + k0] = dv;
}

// dg for canonical gallery tile-pairs. Local row r of this chunk maps to
// pair-tile p = tileOff + (r>>8) -> triangular (ta,tb); rr = r&255:
// g1 = ta*16 + (rr>>4), g2 = tb*16 + (rr&15). Writes dg[r][k] bf16 and
// affmap[r] = g1*256+g2.
__global__ __launch_bounds__(256) void dgprep_kernel(
    const float* __restrict__ X,
    const float* __restrict__ ps, const float* __restrict__ po,
    bf16* __restrict__ dg, int* __restrict__ affmap, int tileOff)
{
    int t  = blockIdx.x * 256 + threadIdx.x;
    int k0 = (t & 127) * 8;
    int r  = t >> 7;
    int p  = tileOff + (r >> 8);
    int ta = 0, rem = p;
    while (rem >= 16 - ta) { rem -= 16 - ta; ++ta; }
    int tb = ta + rem;
    int rr = r & 255;
    int g1 = ta * 16 + (rr >> 4), g2 = tb * 16 + (rr & 15);
    const float* xp = X + (size_t)g1 * 1024 + k0;
    const float* yp = X + (size_t)g2 * 1024 + k0;
    f32x4 x0 = *(const f32x4*)xp, x1 = *(const f32x4*)(xp + 4);
    f32x4 y0 = *(const f32x4*)yp, y1 = *(const f32x4*)(yp + 4);
    f32x4 sa = *(const f32x4*)(ps + k0), sb = *(const f32x4*)(ps + k0 + 4);
    f32x4 oa = *(const f32x4*)(po + k0), ob = *(const f32x4*)(po + k0 + 4);
    bf16x8 dv;
#pragma unroll
    for (int j = 0; j < 4; ++j) {
        float d0 = x0[j] - y0[j];
        float d1 = x1[j] - y1[j];
        dv[j]     = (bf16)(d0 * d0 * sa[j] + oa[j]);
        dv[j + 4] = (bf16)(d1 * d1 * sb[j] + ob[j]);
    }
    *(bf16x8*)&dg[(size_t)r * 1024 + k0] = dv;
    if (k0 == 0) affmap[r] = g1 * 256 + g2;
}

// ---------- gemm128aff (R21-verified): affinity gemm, 2 blocks/CU --------
__global__ __launch_bounds__(256) void gemm128aff(
    const bf16* __restrict__ A,       // dgc [rows][K]
    const bf16* __restrict__ BT,      // sfcT [512][K]
    int K,
    const float* __restrict__ scale, const float* __restrict__ offset,
    const float* __restrict__ sclW, float* __restrict__ w_acc,
    const int* __restrict__ affmap)
{
    __shared__ bf16 As[2 * 128 * 64];   // 32 KiB
    __shared__ bf16 Bs[2 * 128 * 64];   // 32 KiB
    const int tid  = threadIdx.x;
    const int lane = tid & 63;
    const int wave = tid >> 6;
    const int wrow = wave >> 1, wcol = wave & 1;
    const int q = lane >> 4, l16 = lane & 15;

    int bx = blockIdx.x, by = blockIdx.y;
    {
        int nwg = gridDim.x * gridDim.y;
        if ((nwg & 7) == 0) {
            int lin = by * gridDim.x + bx;
            int cpx = nwg >> 3;
            int s = (lin & 7) * cpx + (lin >> 3);
            bx = s % gridDim.x;
            by = s / gridDim.x;
        }
    }
    const int row0 = by * 128;
    const int col0 = bx * 128;

    f32x4 acc[4][4];
#pragma unroll
    for (int mi = 0; mi < 4; ++mi)
#pragma unroll
        for (int ni = 0; ni < 4; ++ni)
#pragma unroll
            for (int e = 0; e < 4; ++e) acc[mi][ni][e] = 0.f;

    auto stageA = [&](int kk, bf16* dst) {
#pragma unroll
        for (int t = 0; t < 4; ++t) {
            int idx = t * 256 + tid;            // 1024 chunks (128 rows x 8)
            int r = idx >> 3, sch = idx & 7;
            int gch = sch ^ (r & 7);
            async_load16(A + (size_t)(row0 + r) * K + kk + gch * 8,
                         &dst[idx * 8]);
        }
    };
    auto stageB = [&](int kk, bf16* dst) {
#pragma unroll
        for (int t = 0; t < 4; ++t) {
            int idx = t * 256 + tid;
            int r = idx >> 3, sch = idx & 7;
            int gch = sch ^ (r & 7);
            async_load16(BT + (size_t)(col0 + r) * K + kk + gch * 8,
                         &dst[idx * 8]);
        }
    };

    stageA(0, As);
    stageB(0, Bs);

    int cur = 0;
    const int nt = K >> 6;
    for (int t = 0; t < nt; ++t) {
        const bool pf = (t + 1) < nt;
        if (pf) {
            stageA((t + 1) * 64, As + (cur ^ 1) * 8192);
            stageB((t + 1) * 64, Bs + (cur ^ 1) * 8192);
        }
        if (pf) {
            asm volatile("s_waitcnt vmcnt(8)\n\ts_barrier" ::: "memory");
        } else {
            asm volatile("s_waitcnt vmcnt(0) lgkmcnt(0)\n\ts_barrier"
                         ::: "memory");
        }
        const bf16* Asb = As + cur * 8192;
        const bf16* Bsb = Bs + cur * 8192;
#pragma unroll
        for (int s = 0; s < 2; ++s) {
            bf16x8 af[4], bfr[4];
#pragma unroll
            for (int mi = 0; mi < 4; ++mi) {
                int r = wrow * 64 + mi * 16 + l16;
                af[mi] = *(const bf16x8*)&Asb[r * 64 + (((s * 4 + q) ^ (r & 7)) * 8)];
            }
#pragma unroll
            for (int ni = 0; ni < 4; ++ni) {
                int rc = wcol * 64 + ni * 16 + l16;
                bfr[ni] = *(const bf16x8*)&Bsb[rc * 64 + (((s * 4 + q) ^ (rc & 7)) * 8)];
            }
#pragma unroll
            for (int mi = 0; mi < 4; ++mi)
#pragma unroll
                for (int ni = 0; ni < 4; ++ni)
                    acc[mi][ni] = __builtin_amdgcn_mfma_f32_16x16x32_bf16(
                        af[mi], bfr[ni], acc[mi][ni], 0, 0, 0);
        }
        if (pf) asm volatile("s_barrier" ::: "memory");
        cur ^= 1;
    }

#pragma unroll
    for (int mi = 0; mi < 4; ++mi)
#pragma unroll
        for (int i = 0; i < 4; ++i) {
            float rs = 0.f;
#pragma unroll
            for (int ni = 0; ni < 4; ++ni) {
                int cc = col0 + wcol * 64 + ni * 16 + l16;
                float val = acc[mi][ni][i] * scale[cc] + offset[cc];
                val = val > 0.f ? val : 0.1f * val;
                rs += val * sclW[cc];
            }
            rs += __shfl_xor(rs, 1, 64);
            rs += __shfl_xor(rs, 2, 64);
            rs += __shfl_xor(rs, 4, 64);
            rs += __shfl_xor(rs, 8, 64);
            if (l16 == 0) {
                int r = row0 + wrow * 64 + mi * 16 + q * 4 + i;
                atomicAdd(w_acc + affmap[r], rs);
            }
        }
}

// One phase: {ds_read A-quad Q (+ all B if READB) ; STAGE ; VM ; barrier ;
//  setprio(1) 16 MFMA setprio(0) ; barrier}. R22: NO explicit lgkmcnt(0) —
// the compiler emits counted lgkmcnt before each dependent MFMA (reads are
// C++ loads, same-thread RAW). All of a phase's reads are consumed by its
// own MFMA cluster, so they complete before the phase-end barrier -> the
// later restage of this buffer (>=2 barriers later) cannot WAR-race them.
#define PHASE(ASB, BSB, Q, READB, STAGE_STMT, VM_STMT)                        \
  {                                                                           \
    if (READB) {                                                              \
      _Pragma("unroll") for (int ni = 0; ni < 4; ++ni) {                      \
        int rc = wcol * 64 + ni * 16 + l16;                                   \
        bfr[ni][0] = *(const bf16x8*)&(BSB)[rc * 64 + (((q) ^ (rc & 7)) * 8)];\
        bfr[ni][1] = *(const bf16x8*)&(BSB)[rc * 64 + (((4 + q) ^ (rc & 7)) * 8)];\
      }                                                                       \
    }                                                                         \
    bf16x8 afq[2][2];                                                         \
    _Pragma("unroll") for (int m2 = 0; m2 < 2; ++m2) {                        \
      int r = wrow * 128 + ((Q) * 2 + m2) * 16 + l16;                         \
      afq[m2][0] = *(const bf16x8*)&(ASB)[r * 64 + (((q) ^ (r & 7)) * 8)];    \
      afq[m2][1] = *(const bf16x8*)&(ASB)[r * 64 + (((4 + q) ^ (r & 7)) * 8)];\
    }                                                                         \
    STAGE_STMT;                                                               \
    VM_STMT;                                                                  \
    __builtin_amdgcn_s_barrier();                                             \
    __builtin_amdgcn_s_setprio(1);                                            \
    _Pragma("unroll") for (int s = 0; s < 2; ++s)                             \
      _Pragma("unroll") for (int m2 = 0; m2 < 2; ++m2)                        \
        _Pragma("unroll") for (int ni = 0; ni < 4; ++ni)                      \
          acc[(Q) * 2 + m2][ni] = __builtin_amdgcn_mfma_f32_16x16x32_bf16(    \
              afq[m2][s], bfr[ni][s], acc[(Q) * 2 + m2][ni], 0, 0, 0);        \
    __builtin_amdgcn_s_setprio(0);                                            \
    __builtin_amdgcn_s_barrier();                                             \
  }

// ---------- gemm256 (8-phase core; R22 epilogue: clsb support) ------------
// C_z[M,N] = epi(A_z[M,K] @ BT_z[N,K]^T). 256x256 block, 512 thr = 8 waves
// (2 row x 4 col), wave 128x64 (acc[8][4]), BK=64, XOR-swizzled LDS,
// buf0 <-> even K-tiles, buf1 <-> odd K-tiles (64 KiB each).
// fuse (fuseW!=0): rs += lrelu(bn(val))*fuseW[col]; one designated
// contributor (col0==0 && wcol==0) adds clsb -> atomicAdd to
// facc[affmap[r]] if affmap else facc[z*faccStride + r].
__global__ __launch_bounds__(512) void gemm256(
    const bf16* __restrict__ A,
    const bf16* __restrict__ BT,
    bf16* __restrict__ C,
    int K, int N,
    long long batchA, long long batchB, long long batchC,
    const float* __restrict__ scale, const float* __restrict__ offset,
    int lrelu,
    const float* __restrict__ fuseW, float* __restrict__ facc,
    long long faccStride,
    const int* __restrict__ affmap,
    const float* __restrict__ clsb)
{
    __shared__ bf16 As[2 * 256 * 64];   // 64 KiB (buf0|buf1)
    __shared__ bf16 Bs[2 * 256 * 64];   // 64 KiB (buf0|buf1)
    const int tid  = threadIdx.x;
    const int lane = tid & 63;
    const int wave = tid >> 6;
    const int wrow = wave >> 2, wcol = wave & 3;
    const int q = lane >> 4, l16 = lane & 15;
    const int z = blockIdx.z;

    // XCD-aware bijective swizzle (x fastest in dispatch order).
    int bx = blockIdx.x, by = blockIdx.y;
    {
        int nwg = gridDim.x * gridDim.y;
        if (gridDim.z == 1 && (nwg & 7) == 0) {
            int lin = by * gridDim.x + bx;
            int cpx = nwg >> 3;
            int s = (lin & 7) * cpx + (lin >> 3);
            bx = s % gridDim.x;
            by = s / gridDim.x;
        }
    }
    const int row0 = by * 256;
    const int col0 = bx * 256;

    const bf16* Ap = A + (size_t)z * (size_t)batchA;
    const bf16* Bp = BT + (size_t)z * (size_t)batchB;

    f32x4 acc[8][4];
#pragma unroll
    for (int mi = 0; mi < 8; ++mi)
#pragma unroll
        for (int ni = 0; ni < 4; ++ni)
#pragma unroll
            for (int e = 0; e < 4; ++e) acc[mi][ni][e] = 0.f;

    // stage one half-tile (rows h*128..h*128+127) = 2 async loads/thread
    auto stageA2 = [&](int kk, int buf, int h) {
#pragma unroll
        for (int tt = 0; tt < 2; ++tt) {
            int idx = (2 * h + tt) * 512 + tid;
            int r = idx >> 3, sch = idx & 7;
            int gch = sch ^ (r & 7);
            async_load16(Ap + (size_t)(row0 + r) * K + kk + gch * 8,
                         &As[buf * 16384 + idx * 8]);
        }
    };
    auto stageB2 = [&](int kk, int buf, int h) {
#pragma unroll
        for (int tt = 0; tt < 2; ++tt) {
            int idx = (2 * h + tt) * 512 + tid;
            int r = idx >> 3, sch = idx & 7;
            int gch = sch ^ (r & 7);
            async_load16(Bp + (size_t)(col0 + r) * K + kk + gch * 8,
                         &Bs[buf * 16384 + idx * 8]);
        }
    };

    // prologue: tile0 (A+B) -> buf0, tile1 B -> buf1  (6 halves, 12 loads)
    stageA2(0, 0, 0); stageA2(0, 0, 1);
    stageB2(0, 0, 0); stageB2(0, 0, 1);
    stageB2(64, 1, 0); stageB2(64, 1, 1);
    // wait buf0's 8 loads (oldest); buf1.B's 4 stay in flight
    asm volatile("s_waitcnt vmcnt(4)" ::: "memory");
    __builtin_amdgcn_s_barrier();

    bf16x8 bfr[4][2];
    const bf16* A0 = As;          const bf16* B0 = Bs;
    const bf16* A1 = As + 16384;  const bf16* B1 = Bs + 16384;
    const int nt = K >> 6;        // even for all call sites (16 or 4)
    for (int i2 = 0; i2 < nt; i2 += 2) {
        const int kk1 = (i2 + 1) << 6, kk2 = (i2 + 2) << 6,
                  kk3 = (i2 + 3) << 6;
        const bool more = (i2 + 2) < nt;   // tiles i2+2 AND i2+3 exist
        // ---- tile i2 from buf0 (phases 1-4) ----
        PHASE(A0, B0, 0, true,  { stageA2(kk1, 1, 0); }, {});
        PHASE(A0, B0, 1, false, { stageA2(kk1, 1, 1); }, {});
        PHASE(A0, B0, 2, false, { if (more) stageB2(kk2, 0, 0); }, {});
        PHASE(A0, B0, 3, false, { if (more) stageB2(kk2, 0, 1); },
              { if (more)
                    asm volatile("s_waitcnt vmcnt(4)" ::: "memory");
                else
                    asm volatile("s_waitcnt vmcnt(0)" ::: "memory"); });
        // ---- tile i2+1 from buf1 (phases 5-8) ----
        PHASE(A1, B1, 0, true,  { if (more) stageA2(kk2, 0, 0); }, {});
        PHASE(A1, B1, 1, false, { if (more) stageA2(kk2, 0, 1); }, {});
        PHASE(A1, B1, 2, false, { if (more) stageB2(kk3, 1, 0); }, {});
        PHASE(A1, B1, 3, false, { if (more) stageB2(kk3, 1, 1); },
              { if (more)
                    asm volatile("s_waitcnt vmcnt(4)" ::: "memory"); });
    }

    // C/D layout (m89-verified): col = lane&15, row = (lane>>4)*4 + reg
    if (fuseW) {
        const float cb = (clsb && col0 == 0 && wcol == 0) ? clsb[0] : 0.f;
#pragma unroll
        for (int mi = 0; mi < 8; ++mi)
#pragma unroll
            for (int i = 0; i < 4; ++i) {
                float rs = 0.f;
#pragma unroll
                for (int ni = 0; ni < 4; ++ni) {
                    int cc = col0 + wcol * 64 + ni * 16 + l16;
                    float val = acc[mi][ni][i] * scale[cc] + offset[cc];
                    val = val > 0.f ? val : 0.1f * val;
                    rs += val * fuseW[cc];
                }
                rs += __shfl_xor(rs, 1, 64);
                rs += __shfl_xor(rs, 2, 64);
                rs += __shfl_xor(rs, 4, 64);
                rs += __shfl_xor(rs, 8, 64);
                if (l16 == 0) {
                    int r = row0 + wrow * 128 + mi * 16 + q * 4 + i;
                    float* dst = affmap ? (facc + affmap[r])
                                        : (facc + (size_t)z * faccStride + r);
                    atomicAdd(dst, rs + cb);
                }
            }
        return;
    }
    bf16* Cp = C + (size_t)z * (size_t)batchC;
#pragma unroll
    for (int mi = 0; mi < 8; ++mi)
#pragma unroll
        for (int ni = 0; ni < 4; ++ni)
#pragma unroll
            for (int i = 0; i < 4; ++i) {
                int r = row0 + wrow * 128 + mi * 16 + q * 4 + i;
                int cc = col0 + wcol * 64 + ni * 16 + l16;
                float val = acc[mi][ni][i];
                if (scale) val = val * scale[cc] + offset[cc];
                if (lrelu) val = val > 0.f ? val : 0.1f * val;
                Cp[(size_t)r * N + cc] = (bf16)val;
            }
}

extern "C" void kernel_launch(void* const* d_in, const int* in_sizes, int n_in,
                              void* d_out, int out_size, void* d_ws, size_t ws_size,
                              hipStream_t stream)
{
    const float* f_p   = (const float*)d_in[0];
    const float* f_g   = (const float*)d_in[1];
    const float* bn_g  = (const float*)d_in[2];
    const float* bn_b  = (const float*)d_in[3];
    const float* bn_m  = (const float*)d_in[4];
    const float* bn_v  = (const float*)d_in[5];
    const float* rf_W1 = (const float*)d_in[6];
    const float* rf_b1 = (const float*)d_in[7];
    const float* rf1_g = (const float*)d_in[8];
    const float* rf1_b = (const float*)d_in[9];
    const float* rf1_m = (const float*)d_in[10];
    const float* rf1_v = (const float*)d_in[11];
    const float* rf_W2 = (const float*)d_in[12];
    const float* rf_b2 = (const float*)d_in[13];
    const float* rf2_g = (const float*)d_in[14];
    const float* rf2_b = (const float*)d_in[15];
    const float* rf2_m = (const float*)d_in[16];
    const float* rf2_v = (const float*)d_in[17];
    const float* sfc_W = (const float*)d_in[18];
    const float* sfc_b = (const float*)d_in[19];
    const float* sbn_g = (const float*)d_in[20];
    const float* sbn_b = (const float*)d_in[21];
    const float* sbn_m = (const float*)d_in[22];
    const float* sbn_v = (const float*)d_in[23];
    const float* scl_W = (const float*)d_in[24];
    const float* scl_b = (const float*)d_in[25];
    const float* ffc_W = (const float*)d_in[26];
    const float* ffc_b = (const float*)d_in[27];
    const float* fbn_g = (const float*)d_in[28];
    const float* fbn_b = (const float*)d_in[29];
    const float* fbn_m = (const float*)d_in[30];
    const float* fbn_v = (const float*)d_in[31];
    const float* cls_W = (const float*)d_in[32];
    const float* cls_b = (const float*)d_in[33];

    const size_t MB = 1ull << 20;
    char* ws = (char*)d_ws;
    float* SC      = (float*)(ws);
    float *s0 = SC,        *o0 = SC + 1024;
    float *s1 = SC + 2048, *o1 = SC + 3072;
    float *s2 = SC + 4096, *o2 = SC + 5120;
    float *s3 = SC + 6144, *o3 = SC + 6656;
    float *s4 = SC + 7168, *o4 = SC + 7680;
    float* w_acc   = (float*)(ws + 65536);       // 256 KiB
    bf16* wT       = (bf16*)(ws + 458752);       // 128 KiB
    int*  affmap   = (int*)(ws + 589824);        // 139 KiB (34816 ints)
    bf16* W1T      = (bf16*)(ws + 1 * MB);
    bf16* W2T      = (bf16*)(ws + 3 * MB);
    bf16* sfcT     = (bf16*)(ws + 5 * MB);
    bf16* ffcT     = (bf16*)(ws + 6 * MB);

    int nc;
    if      (ws_size >= 170 * MB) nc = 1;        // confirmed since R3
    else if (ws_size >= 90 * MB)  nc = 2;
    else                          nc = 4;
    const int pc = 128 / nc;
    const int R  = pc * 256;
    const size_t hbytes = (size_t)R * 1024 * 2;
    bf16* bufA = (bf16*)(ws + 8 * MB);                    // h
    bf16* bufB = (bf16*)(ws + 8 * MB + hbytes);           // d, then t
    bf16* bufC = (bf16*)(ws + 8 * MB + 2 * hbytes);       // uT [pc][512][256]

    // 1. BN folds (one fused launch)
    {
        P5All a;
        a.p[0] = { bn_g,  bn_b,  bn_m,  bn_v,  nullptr, s0, o0 };
        a.p[1] = { rf1_g, rf1_b, rf1_m, rf1_v, rf_b1,   s1, o1 };
        a.p[2] = { rf2_g, rf2_b, rf2_m, rf2_v, rf_b2,   s2, o2 };
        a.p[3] = { sbn_g, sbn_b, sbn_m, sbn_v, sfc_b,   s3, o3 };
        a.p[4] = { fbn_g, fbn_b, fbn_m, fbn_v, ffc_b,   s4, o4 };
        prep5_kernel<<<dim3(16), 256, 0, stream>>>(a);
    }

    // 2. weight transposes (f32 -> bf16), one launch for all 4
    {
        TJobs tj;
        tj.j[0] = { rf_W1, W1T, 1024, 1024 };
        tj.j[1] = { rf_W2, W2T, 1024, 1024 };
        tj.j[2] = { sfc_W, sfcT, 1024, 512 };
        tj.j[3] = { ffc_W, ffcT, 1024, 512 };
        wtrans4_kernel<<<dim3(16, 16, 4), 256, 0, stream>>>(tj);
    }

    // 3. zero accumulators: w_acc, and d_out (feat atomics land there)
    hipMemsetAsync(ws + 65536, 0, 262144, stream);
    hipMemsetAsync(d_out, 0, 131072, stream);

    // 4. symmetric affinity: dgprep materializes dgc, then the 2-blocks/CU
    //    128^2 gemm -> atomicAdd w_acc[affmap[r]]. [R21-verified]
    {
        bf16* dgc = (bf16*)(ws + 8 * MB);    // up to 71.3 MB (na=1)
        const int na = (ws_size >= 170 * MB) ? 1 : 2;
        const int TP = 136 / na;             // pair-tiles per chunk
        for (int ai = 0; ai < na; ++ai) {
            const int rows = TP * 256;
            dgprep_kernel<<<dim3(rows / 2), 256, 0, stream>>>(
                f_g, s0, o0, dgc, affmap + ai * TP * 256, ai * TP);
            gemm128aff<<<dim3(4, rows / 128), 256, 0, stream>>>(
                dgc, sfcT, 1024, s3, o3, scl_W, w_acc,
                affmap + ai * TP * 256);
        }
    }
    // 5. wT[g2][g1] = bf16(w[canon] + scl_b)
    wconv_kernel<<<dim3(256), 256, 0, stream>>>(w_acc, scl_b, wT);

    // 6. probe chunks (all gemms 8-phase; d precomputed into bufB)
    for (int ci = 0; ci < nc; ++ci) {
        // d = bn1((f_p - f_g)^2)        [R,1024] bf16 -> bufB (dead after h)
        dprep_kernel<<<dim3(R / 2), 256, 0, stream>>>(
            f_p, f_g, s0, o0, bufB, ci * R);
        // h = lrelu(rf1(d @ W1 + b1))   [R,1024]
        gemm256<<<dim3(4, R / 256), 512, 0, stream>>>(
            bufB, W1T, bufA, 1024, 1024,
            0, 0, 0, s1, o1, 1, nullptr, nullptr, 0, nullptr, nullptr);
        // t = lrelu(rf2(h @ W2 + b2))   [R,1024] (overwrites d: dead)
        gemm256<<<dim3(4, R / 256), 512, 0, stream>>>(
            bufA, W2T, bufB, 1024, 1024,
            0, 0, 0, s2, o2, 1, nullptr, nullptr, 0, nullptr, nullptr);
        // uT_p = ffcT @ t_p^T           [pc][512][256]  (batched)
        gemm256<<<dim3(1, 2, pc), 512, 0, stream>>>(
            ffcT, bufB, bufC, 1024, 256,
            0, (long long)256 * 1024, (long long)512 * 256,
            nullptr, nullptr, 0, nullptr, nullptr, 0, nullptr, nullptr);
        // feat_p = lrelu(fbn(wT @ uT_p^T + b)) . cls_W (+cls_b once)
        //   -> atomicAdd directly into d_out
        gemm256<<<dim3(2, 1, pc), 512, 0, stream>>>(
            wT, bufC, nullptr, 256, 512,
            0, (long long)512 * 256, 0,
            s4, o4, 1, cls_W, (float*)d_out + (size_t)ci * pc * 256, 256,
            nullptr, cls_b);
    }
}